// Round 1
// baseline (650.735 us; speedup 1.0000x reference)
//
#include <hip/hip_runtime.h>

// GCN3: 3x (COO spmm -> Linear(64) -> ReLU), segment-mean pool, softmax head.
// relu(spmm(X)@W + b) == relu(spmm(X@W) + b): dense transform first, then
// PULL-spmm from fp8 Z (e4m3, 64B/row). Edge records 4B: (col<<8)|fp8(val*16).
// spmm v2: wave = 8 edge-slots x 8 dim-lanes, dwordx2 gathers -> 8 lines in
// flight per VMEM instr (2x v1); persistent grid-stride waves prefetch the
// next row's rp pair (and L3 residuals) under the current row's gathers; NT
// loads on epk/x1/x2 + NT stores on xout keep L2 for the 6.4MB Zq gather set.
// dense64: W column in 64 VGPRs/lane (launch_bounds(256,1) so the allocator
// actually keeps them). CSR build: LDS-staged binpass into 512-row buckets,
// per-bucket counting sort.

#define BSHIFT 9
#define BROWS  (1 << BSHIFT)   // 512 rows per bucket
#define MAXK   256             // supports N <= 131072
#define CHUNK  6144            // edges per binpass/bhist block

typedef float f32x4 __attribute__((ext_vector_type(4)));

__device__ inline unsigned char f2q(float f) {  // fp8 e4m3 RNE
    unsigned p = __builtin_amdgcn_cvt_pk_fp8_f32(f, f, 0u, false);
    return (unsigned char)(p & 0xffu);
}
template <int SEL>
__device__ inline float q2f(unsigned q) {  // byte-select fp8->f32 (SEL = ICE)
    return __builtin_amdgcn_cvt_f32_fp8(q, SEL);
}

// Per-block LDS histogram of bucket ids -> global bucket counts.
__global__ __launch_bounds__(512) void bhist_k(const int* __restrict__ rows,
                                               int* __restrict__ bhist, int E) {
    __shared__ int h[MAXK];
    int tx = threadIdx.x;
    if (tx < MAXK) h[tx] = 0;
    __syncthreads();
    int e0 = blockIdx.x * CHUNK, ee = min(e0 + CHUNK, E);
    for (int e = e0 + tx; e < ee; e += 512)
        atomicAdd(&h[rows[e] >> BSHIFT], 1);
    __syncthreads();
    if (tx < MAXK && h[tx]) atomicAdd(&bhist[tx], h[tx]);
}

// Exclusive scan of bucket counts (single block); init padded cursors; rp[N]=E.
// Also zeroes the pool buffers (sums/cnts) so those memset dispatches go away.
__global__ __launch_bounds__(MAXK) void bscan_k(const int* __restrict__ bhist,
                                                int* __restrict__ bstart,
                                                int* __restrict__ bcur,
                                                int* __restrict__ rp,
                                                float* __restrict__ sums,
                                                int* __restrict__ cnts,
                                                int K, int E, int N, int G) {
    __shared__ int s[MAXK];
    int tx = threadIdx.x;
    // zero pool accumulators (consumed by pool_k much later in the stream)
    f32x4* s4 = (f32x4*)sums;
    for (int i = tx; i < G * 16; i += MAXK) s4[i] = 0;
    for (int i = tx; i < G; i += MAXK) cnts[i] = 0;
    int v = (tx < K) ? bhist[tx] : 0;
    s[tx] = v;
    __syncthreads();
    for (int off = 1; off < MAXK; off <<= 1) {
        int t = (tx >= off) ? s[tx - off] : 0;
        __syncthreads();
        s[tx] += t;
        __syncthreads();
    }
    if (tx < K) {
        bstart[tx] = s[tx] - v;
        bcur[tx * 16] = s[tx] - v;  // 1 cursor per 64B line
    }
    if (tx == K - 1) bstart[K] = E;
    if (tx == 0) rp[N] = E;
}

// Bin edges by 512-row bucket, staged in LDS so global writes are ~31-edge
// single-CU bursts. Record (u64): lo32=(col<<9)|(row&511), hi32=val bits.
__global__ __launch_bounds__(512) void binpass_k(
    const int* __restrict__ rows, const int* __restrict__ cols,
    const float* __restrict__ vals, int* __restrict__ bcur,
    unsigned long long* __restrict__ pk, int E) {
    __shared__ int h[MAXK], base[MAXK], gbase[MAXK], lcnt[MAXK];
    __shared__ unsigned long long st[CHUNK];  // 48 KB
    int tx = threadIdx.x;
    if (tx < MAXK) h[tx] = 0;
    __syncthreads();
    int e0 = blockIdx.x * CHUNK, ee = min(e0 + CHUNK, E);
    for (int e = e0 + tx; e < ee; e += 512)
        atomicAdd(&h[rows[e] >> BSHIFT], 1);
    __syncthreads();
    int v = (tx < MAXK) ? h[tx] : 0;
    if (tx < MAXK) lcnt[tx] = v;  // scan buffer
    __syncthreads();
    for (int off = 1; off < MAXK; off <<= 1) {
        int t = (tx >= off && tx < MAXK) ? lcnt[tx - off] : 0;
        __syncthreads();
        if (tx < MAXK) lcnt[tx] += t;
        __syncthreads();
    }
    if (tx < MAXK) {
        base[tx] = lcnt[tx] - v;
        if (v) gbase[tx] = atomicAdd(&bcur[tx * 16], v);
        lcnt[tx] = 0;
    }
    __syncthreads();
    for (int e = e0 + tx; e < ee; e += 512) {
        int r = rows[e];
        int c = cols[e];
        float vv = vals[e];
        int b = r >> BSHIFT;
        int p = base[b] + atomicAdd(&lcnt[b], 1);
        unsigned lo = ((unsigned)c << BSHIFT) | (unsigned)(r & (BROWS - 1));
        st[p] = (unsigned long long)lo
              | ((unsigned long long)(unsigned)__float_as_int(vv) << 32);
    }
    __syncthreads();
    // flush contiguous per-bucket runs, wave-parallel. NT safe: 64 lanes x 8B
    // = 512B contiguous per instruction (full lines covered).
    int lane = tx & 63, wid = tx >> 6;
    for (int b = wid; b < MAXK; b += 8) {
        int cnt = h[b];
        if (!cnt) continue;
        int lb = base[b], gb = gbase[b];
        for (int i = lane; i < cnt; i += 64)
            __builtin_nontemporal_store(st[lb + i], &pk[gb + i]);
    }
}

// Per-bucket counting sort: one block per bucket. LDS hist over 512 rows,
// scan -> rp, then local scatter into the bucket's contiguous epk window.
// CACHED loads/stores (sub-line scatter: L2 must assemble the lines).
// Output record (4B): (col << 8) | fp8(val * 16).
__global__ __launch_bounds__(512) void sort_k(
    const int* __restrict__ bstart, const unsigned long long* __restrict__ pk,
    int* __restrict__ rp, unsigned* __restrict__ epk, int n) {
    __shared__ int hist[BROWS], cur[BROWS];
    int tx = threadIdx.x;
    int b = blockIdx.x;
    int row0 = b << BSHIFT;
    int s = bstart[b], e = bstart[b + 1];
    hist[tx] = 0;
    __syncthreads();
    for (int j = s + tx; j < e; j += 512) {
        unsigned lo = (unsigned)pk[j];
        atomicAdd(&hist[lo & (BROWS - 1)], 1);
    }
    __syncthreads();
    int v = hist[tx];
    for (int off = 1; off < BROWS; off <<= 1) {
        int t = (tx >= off) ? hist[tx - off] : 0;
        __syncthreads();
        hist[tx] += t;
        __syncthreads();
    }
    int excl = hist[tx] - v;
    cur[tx] = excl;
    if (row0 + tx < n) rp[row0 + tx] = s + excl;
    __syncthreads();
    for (int j = s + tx; j < e; j += 512) {
        unsigned long long rec = pk[j];
        unsigned lo = (unsigned)rec;
        float vv = __int_as_float((int)(unsigned)(rec >> 32));
        int r = (int)(lo & (BROWS - 1));
        int q = atomicAdd(&cur[r], 1);
        epk[s + q] = ((lo >> BSHIFT) << 8) | (unsigned)f2q(vv * 16.f);
    }
}

// Zq = fp8(X @ W1), X:[n,5]. Wave per row, lane = out dim.
__global__ __launch_bounds__(256) void dense5_k(
    const float* __restrict__ X, const float* __restrict__ W,
    unsigned char* __restrict__ Zq, int n) {
    int lane = threadIdx.x & 63;
    int row = (blockIdx.x * blockDim.x + threadIdx.x) >> 6;
    if (row >= n) return;
    float w0 = W[lane], w1 = W[64 + lane], w2 = W[128 + lane],
          w3 = W[192 + lane], w4 = W[256 + lane];
    float xv = (lane < 5) ? X[(size_t)row * 5 + lane] : 0.f;
    float y = __shfl(xv, 0, 64) * w0;
    y = fmaf(__shfl(xv, 1, 64), w1, y);
    y = fmaf(__shfl(xv, 2, 64), w2, y);
    y = fmaf(__shfl(xv, 3, 64), w3, y);
    y = fmaf(__shfl(xv, 4, 64), w4, y);
    Zq[(size_t)row * 64 + lane] = f2q(y);
}

// Zq = fp8(X @ W): W column `lane` in 64 VGPRs. launch_bounds(256,1) lets the
// allocator keep all 64 live. Grid 1024 blocks = 16 waves/CU; ~24 rows/wave
// amortizes the W load. Per row: 16 wave-uniform float4 loads + 64 fmaf.
__global__ __launch_bounds__(256, 1) void dense64_k(
    const float* __restrict__ X, const float* __restrict__ W,
    unsigned char* __restrict__ Zq, int n) {
    int lane = threadIdx.x & 63, wid = threadIdx.x >> 6;
    float wr[64];
#pragma unroll
    for (int k = 0; k < 64; ++k) wr[k] = W[k * 64 + lane];
    int wave = blockIdx.x * 4 + wid;
    int nw = gridDim.x * 4;
    for (int row = wave; row < n; row += nw) {
        const float4* xr = (const float4*)(X + (size_t)row * 64);
        float y = 0.f;
#pragma unroll
        for (int k4 = 0; k4 < 16; ++k4) {
            float4 xv = xr[k4];  // wave-uniform broadcast
            y = fmaf(xv.x, wr[k4 * 4 + 0], y);
            y = fmaf(xv.y, wr[k4 * 4 + 1], y);
            y = fmaf(xv.z, wr[k4 * 4 + 2], y);
            y = fmaf(xv.w, wr[k4 * 4 + 3], y);
        }
        Zq[(size_t)row * 64 + lane] = f2q(y);
    }
}

// spmm v2 core: 8 fp8 dims per lane, 8 edge-slots per wave. One dwordx2
// gather = 8 edges = 8 distinct 64B Zq lines in flight.
#define ACC8(P, cg, d)                                                         \
    {                                                                          \
        float v = q2f<0>(cg);                                                  \
        P##0 = fmaf(v, q2f<0>((d).x), P##0);                                   \
        P##1 = fmaf(v, q2f<1>((d).x), P##1);                                   \
        P##2 = fmaf(v, q2f<2>((d).x), P##2);                                   \
        P##3 = fmaf(v, q2f<3>((d).x), P##3);                                   \
        P##4 = fmaf(v, q2f<0>((d).y), P##4);                                   \
        P##5 = fmaf(v, q2f<1>((d).y), P##5);                                   \
        P##6 = fmaf(v, q2f<2>((d).y), P##6);                                   \
        P##7 = fmaf(v, q2f<3>((d).y), P##7);                                   \
    }

// xout[row] = relu(spmm/16 + b)  (+ xa + xb when L3: fused h = relu+x1+x2).
// Persistent grid-stride waves: next row's rp pair (and L3 residual reads)
// issue before the current row's gather loop -> their latency hides under
// the gathers. epk/xa/xb are NT (streaming; keep L2 for Zq); Zq gathers
// stay cached.
template <int L3>
__global__ __launch_bounds__(256) void spmm8_k(
    const int* __restrict__ rp, const unsigned* __restrict__ epk,
    const unsigned char* __restrict__ Zq, const float* __restrict__ bias,
    const float* __restrict__ xa, const float* __restrict__ xb,
    float* __restrict__ xout, int n) {
    int lane = threadIdx.x & 63;
    int dimoct = lane & 7, slot = lane >> 3;
    const unsigned char* zb = Zq + (dimoct << 3);
    int wave = (int)((blockIdx.x * blockDim.x + threadIdx.x) >> 6);
    int nw = (int)((gridDim.x * blockDim.x) >> 6);
    if (wave >= n) return;
    const f32x4* b4 = (const f32x4*)bias;
    f32x4 bv0 = b4[dimoct * 2];
    f32x4 bv1 = b4[dimoct * 2 + 1];
    int s = rp[wave], e = rp[wave + 1];
    int row = wave;
    while (true) {
        int nrow = row + nw;
        int s2 = 0, e2 = 0;
        if (nrow < n) {  // prefetch next row's extent under this row's work
            s2 = rp[nrow];
            e2 = rp[nrow + 1];
        }
        f32x4 a0 = 0, a1 = 0, r0 = 0, r1 = 0;
        if (L3) {  // residual reads issue before the gather loop
            const f32x4* pa = (const f32x4*)(xa + (size_t)row * 64) + dimoct * 2;
            const f32x4* pb = (const f32x4*)(xb + (size_t)row * 64) + dimoct * 2;
            a0 = __builtin_nontemporal_load(pa);
            a1 = __builtin_nontemporal_load(pa + 1);
            r0 = __builtin_nontemporal_load(pb);
            r1 = __builtin_nontemporal_load(pb + 1);
        }
        float t0 = 0.f, t1 = 0.f, t2 = 0.f, t3 = 0.f,
              t4 = 0.f, t5 = 0.f, t6 = 0.f, t7 = 0.f;
        float u0 = 0.f, u1 = 0.f, u2 = 0.f, u3 = 0.f,
              u4 = 0.f, u5 = 0.f, u6 = 0.f, u7 = 0.f;
        int j = s;
        for (; j + 32 <= e; j += 32) {  // 32 edges: 4 c-loads + 4 gathers
            unsigned g0 = __builtin_nontemporal_load(epk + j + slot);
            unsigned g1 = __builtin_nontemporal_load(epk + j + 8 + slot);
            unsigned g2 = __builtin_nontemporal_load(epk + j + 16 + slot);
            unsigned g3 = __builtin_nontemporal_load(epk + j + 24 + slot);
            uint2 d0 = *(const uint2*)(zb + ((g0 >> 8) << 6));
            uint2 d1 = *(const uint2*)(zb + ((g1 >> 8) << 6));
            uint2 d2 = *(const uint2*)(zb + ((g2 >> 8) << 6));
            uint2 d3 = *(const uint2*)(zb + ((g3 >> 8) << 6));
            ACC8(t, g0, d0)
            ACC8(u, g1, d1)
            ACC8(t, g2, d2)
            ACC8(u, g3, d3)
        }
        for (; j + 8 <= e; j += 8) {
            unsigned g = __builtin_nontemporal_load(epk + j + slot);
            uint2 d = *(const uint2*)(zb + ((g >> 8) << 6));
            ACC8(t, g, d)
        }
        if (j < e) {  // guarded tail: c=0 -> col 0, fp8 val 0x00 = 0.0
            int idx = j + slot;
            unsigned g = (idx < e) ? epk[idx] : 0u;
            uint2 d = *(const uint2*)(zb + ((g >> 8) << 6));
            ACC8(u, g, d)
        }
        t0 += u0; t1 += u1; t2 += u2; t3 += u3;
        t4 += u4; t5 += u5; t6 += u6; t7 += u7;
        // butterfly over slot bits (lane bits 3..5)
        t0 += __shfl_xor(t0, 8, 64);  t1 += __shfl_xor(t1, 8, 64);
        t2 += __shfl_xor(t2, 8, 64);  t3 += __shfl_xor(t3, 8, 64);
        t4 += __shfl_xor(t4, 8, 64);  t5 += __shfl_xor(t5, 8, 64);
        t6 += __shfl_xor(t6, 8, 64);  t7 += __shfl_xor(t7, 8, 64);
        t0 += __shfl_xor(t0, 16, 64); t1 += __shfl_xor(t1, 16, 64);
        t2 += __shfl_xor(t2, 16, 64); t3 += __shfl_xor(t3, 16, 64);
        t4 += __shfl_xor(t4, 16, 64); t5 += __shfl_xor(t5, 16, 64);
        t6 += __shfl_xor(t6, 16, 64); t7 += __shfl_xor(t7, 16, 64);
        t0 += __shfl_xor(t0, 32, 64); t1 += __shfl_xor(t1, 32, 64);
        t2 += __shfl_xor(t2, 32, 64); t3 += __shfl_xor(t3, 32, 64);
        t4 += __shfl_xor(t4, 32, 64); t5 += __shfl_xor(t5, 32, 64);
        t6 += __shfl_xor(t6, 32, 64); t7 += __shfl_xor(t7, 32, 64);
        if (slot == 0) {  // lanes 0..7: dims dimoct*8 .. +7
            f32x4 o0, o1;
            o0.x = fmaxf(fmaf(t0, 0.0625f, bv0.x), 0.f);
            o0.y = fmaxf(fmaf(t1, 0.0625f, bv0.y), 0.f);
            o0.z = fmaxf(fmaf(t2, 0.0625f, bv0.z), 0.f);
            o0.w = fmaxf(fmaf(t3, 0.0625f, bv0.w), 0.f);
            o1.x = fmaxf(fmaf(t4, 0.0625f, bv1.x), 0.f);
            o1.y = fmaxf(fmaf(t5, 0.0625f, bv1.y), 0.f);
            o1.z = fmaxf(fmaf(t6, 0.0625f, bv1.z), 0.f);
            o1.w = fmaxf(fmaf(t7, 0.0625f, bv1.w), 0.f);
            if (L3) {
                o0 += a0 + r0;
                o1 += a1 + r1;
            }
            f32x4* op = (f32x4*)(xout + (size_t)row * 64) + dimoct * 2;
            __builtin_nontemporal_store(o0, op);
            __builtin_nontemporal_store(o1, op + 1);
        }
        if (nrow >= n) break;
        row = nrow; s = s2; e = e2;
    }
}

// Pool: batch sorted -> run-length accumulate 64 nodes per wave, one
// atomicAdd per segment boundary per lane. h already = x1+x2+x3.
__global__ void pool_k(const float* __restrict__ h, const int* __restrict__ batch,
                       float* __restrict__ sums, int* __restrict__ cnts, int n) {
    int lane = threadIdx.x & 63;
    int w = (blockIdx.x * blockDim.x + threadIdx.x) >> 6;
    int node0 = w * 64;
    if (node0 >= n) return;
    int cur = batch[node0];
    float acc = 0.f;
    int cnt = 0;
    int end = min(node0 + 64, n);
    for (int nd = node0; nd < end; ++nd) {
        int bg = batch[nd];  // wave-uniform
        if (bg != cur) {
            atomicAdd(&sums[(size_t)cur * 64 + lane], acc);
            if (lane == 0) atomicAdd(&cnts[cur], cnt);
            acc = 0.f;
            cnt = 0;
            cur = bg;
        }
        acc += h[(size_t)nd * 64 + lane];
        cnt++;
    }
    atomicAdd(&sums[(size_t)cur * 64 + lane], acc);
    if (lane == 0) atomicAdd(&cnts[cur], cnt);
}

// Head: pooled = sums/(3*cnt); out = softmax(pooled @ Wl + bl). Wave per graph.
__global__ void final_k(const float* __restrict__ sums, const int* __restrict__ cnts,
                        const float* __restrict__ Wl, const float* __restrict__ bl,
                        float* __restrict__ out, int G) {
    int lane = threadIdx.x & 63;
    int g = (blockIdx.x * blockDim.x + threadIdx.x) >> 6;
    if (g >= G) return;
    float c = (float)max(cnts[g], 1);
    float s = sums[(size_t)g * 64 + lane] / (3.f * c);
    float y = (lane < 10) ? bl[lane] : -1e30f;
    for (int k = 0; k < 64; ++k) {
        float sk = __shfl(s, k, 64);
        if (lane < 10) y = fmaf(sk, Wl[k * 10 + lane], y);
    }
    float m = y;
#pragma unroll
    for (int off = 8; off; off >>= 1) m = fmaxf(m, __shfl_xor(m, off, 16));
    float ey = (lane < 10) ? __expf(y - m) : 0.f;
    float sm = ey;
#pragma unroll
    for (int off = 8; off; off >>= 1) sm += __shfl_xor(sm, off, 16);
    if (lane < 10) out[(size_t)g * 10 + lane] = ey / sm;
}

extern "C" void kernel_launch(void* const* d_in, const int* in_sizes, int n_in,
                              void* d_out, int out_size, void* d_ws, size_t ws_size,
                              hipStream_t stream) {
    const float* x = (const float*)d_in[0];
    const int* rows = (const int*)d_in[1];
    const int* cols = (const int*)d_in[2];
    const float* vals = (const float*)d_in[3];
    const int* batch = (const int*)d_in[4];
    const float* W1 = (const float*)d_in[5];
    const float* b1 = (const float*)d_in[6];
    const float* W2 = (const float*)d_in[7];
    const float* b2 = (const float*)d_in[8];
    const float* W3 = (const float*)d_in[9];
    const float* b3 = (const float*)d_in[10];
    const float* Wl = (const float*)d_in[11];
    const float* bl = (const float*)d_in[12];
    float* out = (float*)d_out;

    const int N = in_sizes[4];   // n_nodes (<= 131072)
    const int E = in_sizes[1];   // n_edges
    const int G = out_size / 10; // n_graphs
    const int K = (N + BROWS - 1) >> BSHIFT;

    char* p = (char*)d_ws;
    size_t off = 0;
    auto alloc = [&](size_t bytes) -> void* {
        off = (off + 255) & ~(size_t)255;
        void* r = (void*)(p + off);
        off += bytes;
        return r;
    };
    size_t featF = (size_t)N * 64 * 4;
    int* bhist = (int*)alloc(MAXK * 4);
    int* bstart = (int*)alloc((MAXK + 1) * 4);
    int* bcur = (int*)alloc(MAXK * 16 * 4);
    int* rp = (int*)alloc((size_t)(N + 1) * 4);
    // pk (bucketed, pre-sort) is dead after sort_k; alias with h (written
    // only by the layer-3 spmm, far after sort_k).
    void* regP = alloc((size_t)E * 8 > featF ? (size_t)E * 8 : featF);
    unsigned* epk = (unsigned*)alloc((size_t)E * 4);  // packed sorted edges
    unsigned char* ZqA = (unsigned char*)alloc((size_t)N * 64);
    unsigned char* ZqB = (unsigned char*)alloc((size_t)N * 64);
    float* x1 = (float*)alloc(featF);
    float* x2 = (float*)alloc(featF);
    float* sums = (float*)alloc((size_t)G * 64 * 4);
    int* cnts = (int*)alloc((size_t)G * 4);

    unsigned long long* pk = (unsigned long long*)regP;
    float* h = (float*)regP;

    hipMemsetAsync(bhist, 0, MAXK * 4, stream);

    int cb = (E + CHUNK - 1) / CHUNK;
    bhist_k<<<cb, 512, 0, stream>>>(rows, bhist, E);
    bscan_k<<<1, MAXK, 0, stream>>>(bhist, bstart, bcur, rp, sums, cnts, K, E, N, G);
    binpass_k<<<cb, 512, 0, stream>>>(rows, cols, vals, bcur, pk, E);
    sort_k<<<K, 512, 0, stream>>>(bstart, pk, rp, epk, N);

    int rb = (N + 3) / 4;  // wave-per-row blocks (dense5)
    int sg = rb < 2048 ? (rb < 1 ? 1 : rb) : 2048;  // persistent spmm grid
    dense5_k<<<rb, 256, 0, stream>>>(x, W1, ZqA, N);
    spmm8_k<0><<<sg, 256, 0, stream>>>(rp, epk, ZqA, b1, nullptr, nullptr, x1, N);
    dense64_k<<<1024, 256, 0, stream>>>(x1, W2, ZqB, N);
    spmm8_k<0><<<sg, 256, 0, stream>>>(rp, epk, ZqB, b2, nullptr, nullptr, x2, N);
    dense64_k<<<1024, 256, 0, stream>>>(x2, W3, ZqA, N);
    spmm8_k<1><<<sg, 256, 0, stream>>>(rp, epk, ZqA, b3, x1, x2, h, N);

    int pw = (N + 63) / 64;
    pool_k<<<(pw + 3) / 4, 256, 0, stream>>>(h, batch, sums, cnts, N);
    final_k<<<(G + 3) / 4, 256, 0, stream>>>(sums, cnts, Wl, bl, out, G);
}

// Round 3
// 535.413 us; speedup vs baseline: 1.2154x; 1.2154x over previous
//
#include <hip/hip_runtime.h>

// GCN3: 3x (COO spmm -> Linear(64) -> ReLU), segment-mean pool, softmax head.
// relu(spmm(X)@W + b) == relu(spmm(X@W) + b): dense transform first, then
// PULL-spmm from fp8 Z (e4m3, 64B/row). Edge records 4B: (col<<8)|fp8(val*16).
// spmm v3: v1's proven wave shape (4 edge-slots x 16 dim-lanes, dword
// gathers, short waves, big grid for turnover) + TWO independent rows per
// wave with interleaved chains: 8 c-loads then 8 gathers per iter across
// both rows -> 32 lines in flight, 2x issue work per wave, same 1-chain
// critical path. (v2's persistent grid-stride was sequential-per-row = no
// real overlap, and the exact-fill grid killed wave turnover: occ 65->37.)
// NT loads on epk/x1/x2 keep L2 for the 6.4MB Zq gather set (-13MB FETCH).
// NT builtins require ext_vector types, NOT HIP_vector_type (float4).
// dense64: W column in 64 VGPRs/lane (launch_bounds(256,1)).
// CSR build: LDS-staged binpass into 512-row buckets, per-bucket counting sort.

#define BSHIFT 9
#define BROWS  (1 << BSHIFT)   // 512 rows per bucket
#define MAXK   256             // supports N <= 131072
#define CHUNK  6144            // edges per binpass/bhist block

typedef float f32x4 __attribute__((ext_vector_type(4)));

__device__ inline unsigned char f2q(float f) {  // fp8 e4m3 RNE
    unsigned p = __builtin_amdgcn_cvt_pk_fp8_f32(f, f, 0u, false);
    return (unsigned char)(p & 0xffu);
}
template <int SEL>
__device__ inline float q2f(unsigned q) {  // byte-select fp8->f32 (SEL = ICE)
    return __builtin_amdgcn_cvt_f32_fp8(q, SEL);
}

// Per-block LDS histogram of bucket ids -> global bucket counts.
__global__ __launch_bounds__(512) void bhist_k(const int* __restrict__ rows,
                                               int* __restrict__ bhist, int E) {
    __shared__ int h[MAXK];
    int tx = threadIdx.x;
    if (tx < MAXK) h[tx] = 0;
    __syncthreads();
    int e0 = blockIdx.x * CHUNK, ee = min(e0 + CHUNK, E);
    for (int e = e0 + tx; e < ee; e += 512)
        atomicAdd(&h[rows[e] >> BSHIFT], 1);
    __syncthreads();
    if (tx < MAXK && h[tx]) atomicAdd(&bhist[tx], h[tx]);
}

// Exclusive scan of bucket counts (single block); init padded cursors; rp[N]=E.
// Also zeroes the pool buffers (sums/cnts) so those memset dispatches go away.
__global__ __launch_bounds__(MAXK) void bscan_k(const int* __restrict__ bhist,
                                                int* __restrict__ bstart,
                                                int* __restrict__ bcur,
                                                int* __restrict__ rp,
                                                float* __restrict__ sums,
                                                int* __restrict__ cnts,
                                                int K, int E, int N, int G) {
    __shared__ int s[MAXK];
    int tx = threadIdx.x;
    f32x4* s4 = (f32x4*)sums;
    for (int i = tx; i < G * 16; i += MAXK) s4[i] = 0;
    for (int i = tx; i < G; i += MAXK) cnts[i] = 0;
    int v = (tx < K) ? bhist[tx] : 0;
    s[tx] = v;
    __syncthreads();
    for (int off = 1; off < MAXK; off <<= 1) {
        int t = (tx >= off) ? s[tx - off] : 0;
        __syncthreads();
        s[tx] += t;
        __syncthreads();
    }
    if (tx < K) {
        bstart[tx] = s[tx] - v;
        bcur[tx * 16] = s[tx] - v;  // 1 cursor per 64B line
    }
    if (tx == K - 1) bstart[K] = E;
    if (tx == 0) rp[N] = E;
}

// Bin edges by 512-row bucket, staged in LDS so global writes are ~31-edge
// single-CU bursts. Record (u64): lo32=(col<<9)|(row&511), hi32=val bits.
__global__ __launch_bounds__(512) void binpass_k(
    const int* __restrict__ rows, const int* __restrict__ cols,
    const float* __restrict__ vals, int* __restrict__ bcur,
    unsigned long long* __restrict__ pk, int E) {
    __shared__ int h[MAXK], base[MAXK], gbase[MAXK], lcnt[MAXK];
    __shared__ unsigned long long st[CHUNK];  // 48 KB
    int tx = threadIdx.x;
    if (tx < MAXK) h[tx] = 0;
    __syncthreads();
    int e0 = blockIdx.x * CHUNK, ee = min(e0 + CHUNK, E);
    for (int e = e0 + tx; e < ee; e += 512)
        atomicAdd(&h[rows[e] >> BSHIFT], 1);
    __syncthreads();
    int v = (tx < MAXK) ? h[tx] : 0;
    if (tx < MAXK) lcnt[tx] = v;  // scan buffer
    __syncthreads();
    for (int off = 1; off < MAXK; off <<= 1) {
        int t = (tx >= off && tx < MAXK) ? lcnt[tx - off] : 0;
        __syncthreads();
        if (tx < MAXK) lcnt[tx] += t;
        __syncthreads();
    }
    if (tx < MAXK) {
        base[tx] = lcnt[tx] - v;
        if (v) gbase[tx] = atomicAdd(&bcur[tx * 16], v);
        lcnt[tx] = 0;
    }
    __syncthreads();
    for (int e = e0 + tx; e < ee; e += 512) {
        int r = rows[e];
        int c = cols[e];
        float vv = vals[e];
        int b = r >> BSHIFT;
        int p = base[b] + atomicAdd(&lcnt[b], 1);
        unsigned lo = ((unsigned)c << BSHIFT) | (unsigned)(r & (BROWS - 1));
        st[p] = (unsigned long long)lo
              | ((unsigned long long)(unsigned)__float_as_int(vv) << 32);
    }
    __syncthreads();
    // flush contiguous per-bucket runs, wave-parallel. NT safe: 64 lanes x 8B
    // = 512B contiguous per instruction (full lines covered).
    int lane = tx & 63, wid = tx >> 6;
    for (int b = wid; b < MAXK; b += 8) {
        int cnt = h[b];
        if (!cnt) continue;
        int lb = base[b], gb = gbase[b];
        for (int i = lane; i < cnt; i += 64)
            __builtin_nontemporal_store(st[lb + i], &pk[gb + i]);
    }
}

// Per-bucket counting sort: one block per bucket. LDS hist over 512 rows,
// scan -> rp, then local scatter into the bucket's contiguous epk window.
// CACHED loads/stores (sub-line scatter: L2 must assemble the lines).
// Output record (4B): (col << 8) | fp8(val * 16).
__global__ __launch_bounds__(512) void sort_k(
    const int* __restrict__ bstart, const unsigned long long* __restrict__ pk,
    int* __restrict__ rp, unsigned* __restrict__ epk, int n) {
    __shared__ int hist[BROWS], cur[BROWS];
    int tx = threadIdx.x;
    int b = blockIdx.x;
    int row0 = b << BSHIFT;
    int s = bstart[b], e = bstart[b + 1];
    hist[tx] = 0;
    __syncthreads();
    for (int j = s + tx; j < e; j += 512) {
        unsigned lo = (unsigned)pk[j];
        atomicAdd(&hist[lo & (BROWS - 1)], 1);
    }
    __syncthreads();
    int v = hist[tx];
    for (int off = 1; off < BROWS; off <<= 1) {
        int t = (tx >= off) ? hist[tx - off] : 0;
        __syncthreads();
        hist[tx] += t;
        __syncthreads();
    }
    int excl = hist[tx] - v;
    cur[tx] = excl;
    if (row0 + tx < n) rp[row0 + tx] = s + excl;
    __syncthreads();
    for (int j = s + tx; j < e; j += 512) {
        unsigned long long rec = pk[j];
        unsigned lo = (unsigned)rec;
        float vv = __int_as_float((int)(unsigned)(rec >> 32));
        int r = (int)(lo & (BROWS - 1));
        int q = atomicAdd(&cur[r], 1);
        epk[s + q] = ((lo >> BSHIFT) << 8) | (unsigned)f2q(vv * 16.f);
    }
}

// Zq = fp8(X @ W1), X:[n,5]. Wave per row, lane = out dim.
__global__ __launch_bounds__(256) void dense5_k(
    const float* __restrict__ X, const float* __restrict__ W,
    unsigned char* __restrict__ Zq, int n) {
    int lane = threadIdx.x & 63;
    int row = (blockIdx.x * blockDim.x + threadIdx.x) >> 6;
    if (row >= n) return;
    float w0 = W[lane], w1 = W[64 + lane], w2 = W[128 + lane],
          w3 = W[192 + lane], w4 = W[256 + lane];
    float xv = (lane < 5) ? X[(size_t)row * 5 + lane] : 0.f;
    float y = __shfl(xv, 0, 64) * w0;
    y = fmaf(__shfl(xv, 1, 64), w1, y);
    y = fmaf(__shfl(xv, 2, 64), w2, y);
    y = fmaf(__shfl(xv, 3, 64), w3, y);
    y = fmaf(__shfl(xv, 4, 64), w4, y);
    Zq[(size_t)row * 64 + lane] = f2q(y);
}

// Zq = fp8(X @ W): W column `lane` in 64 VGPRs. launch_bounds(256,1) lets the
// allocator keep all 64 live. Grid 1024 blocks = 16 waves/CU; ~24 rows/wave
// amortizes the W load. Per row: 16 wave-uniform float4 loads + 64 fmaf.
__global__ __launch_bounds__(256, 1) void dense64_k(
    const float* __restrict__ X, const float* __restrict__ W,
    unsigned char* __restrict__ Zq, int n) {
    int lane = threadIdx.x & 63, wid = threadIdx.x >> 6;
    float wr[64];
#pragma unroll
    for (int k = 0; k < 64; ++k) wr[k] = W[k * 64 + lane];
    int wave = blockIdx.x * 4 + wid;
    int nw = gridDim.x * 4;
    for (int row = wave; row < n; row += nw) {
        const f32x4* xr = (const f32x4*)(X + (size_t)row * 64);
        float y = 0.f;
#pragma unroll
        for (int k4 = 0; k4 < 16; ++k4) {
            f32x4 xv = xr[k4];  // wave-uniform broadcast
            y = fmaf(xv.x, wr[k4 * 4 + 0], y);
            y = fmaf(xv.y, wr[k4 * 4 + 1], y);
            y = fmaf(xv.z, wr[k4 * 4 + 2], y);
            y = fmaf(xv.w, wr[k4 * 4 + 3], y);
        }
        Zq[(size_t)row * 64 + lane] = f2q(y);
    }
}

// One edge's contribution: dword gather from Zq row (16 dim-lanes x 4B cover
// the 64B line), 4 fp8->f32 + 4 fmaf.
#define GG(cg, A0, A1, A2, A3)                                                 \
    {                                                                          \
        unsigned d = *(const unsigned*)(Zq + (((cg) >> 8) << 6) + (dim4 << 2));\
        float v = q2f<0>((cg));                                                \
        A0 = fmaf(v, q2f<0>(d), A0);                                           \
        A1 = fmaf(v, q2f<1>(d), A1);                                           \
        A2 = fmaf(v, q2f<2>(d), A2);                                           \
        A3 = fmaf(v, q2f<3>(d), A3);                                           \
    }

// spmm v3: wave = 2 independent rows, each 4 edge-slots x 16 dim-lanes.
// Common phase interleaves both rows (8 c-loads -> 8 gathers -> 16 edges'
// FMA work per iter); remainders finish each row solo. Guarded tail uses
// c=0 (col 0, fp8 0x00 = 0.0 -> contributes nothing).
template <int L3>
__global__ __launch_bounds__(256) void spmm2_k(
    const int* __restrict__ rp, const unsigned* __restrict__ epk,
    const unsigned char* __restrict__ Zq, const float* __restrict__ bias,
    const float* __restrict__ xa, const float* __restrict__ xb,
    float* __restrict__ xout, int n) {
    int lane = threadIdx.x & 63;
    int dim4 = lane & 15, slot = lane >> 4;
    int w = (int)((blockIdx.x * blockDim.x + threadIdx.x) >> 6);
    int r0 = w * 2;
    if (r0 >= n) return;
    bool has1 = (r0 + 1) < n;
    int2 se = *(const int2*)(rp + r0);  // 8B-aligned: r0 even, rp 256-aligned
    int s0 = se.x, e0 = se.y;
    int e1 = has1 ? rp[r0 + 2] : e0;

    float t0 = 0.f, t1 = 0.f, t2 = 0.f, t3 = 0.f;   // row0 even groups
    float u0 = 0.f, u1 = 0.f, u2 = 0.f, u3 = 0.f;   // row0 odd groups
    float p0 = 0.f, p1 = 0.f, p2 = 0.f, p3 = 0.f;   // row1 even groups
    float q0 = 0.f, q1 = 0.f, q2 = 0.f, q3 = 0.f;   // row1 odd groups
    int j0 = s0, j1 = e0;
    // interleaved common phase: 16 edges per row per iter, 8 lines in flight
    // per gather batch across two INDEPENDENT chains.
    for (; j0 + 16 <= e0 && j1 + 16 <= e1; j0 += 16, j1 += 16) {
        unsigned c[8];
#pragma unroll
        for (int g = 0; g < 4; ++g)
            c[g] = __builtin_nontemporal_load(epk + j0 + g * 4 + slot);
#pragma unroll
        for (int g = 0; g < 4; ++g)
            c[4 + g] = __builtin_nontemporal_load(epk + j1 + g * 4 + slot);
        GG(c[0], t0, t1, t2, t3)
        GG(c[1], u0, u1, u2, u3)
        GG(c[4], p0, p1, p2, p3)
        GG(c[5], q0, q1, q2, q3)
        GG(c[2], t0, t1, t2, t3)
        GG(c[3], u0, u1, u2, u3)
        GG(c[6], p0, p1, p2, p3)
        GG(c[7], q0, q1, q2, q3)
    }
    // row0 remainder
    for (; j0 + 16 <= e0; j0 += 16) {
        unsigned c[4];
#pragma unroll
        for (int g = 0; g < 4; ++g)
            c[g] = __builtin_nontemporal_load(epk + j0 + g * 4 + slot);
        GG(c[0], t0, t1, t2, t3)
        GG(c[1], u0, u1, u2, u3)
        GG(c[2], t0, t1, t2, t3)
        GG(c[3], u0, u1, u2, u3)
    }
    for (; j0 + 4 <= e0; j0 += 4) {
        unsigned cc = __builtin_nontemporal_load(epk + j0 + slot);
        GG(cc, t0, t1, t2, t3)
    }
    if (j0 < e0) {
        int idx = j0 + slot;
        unsigned cc = (idx < e0) ? epk[idx] : 0u;
        GG(cc, u0, u1, u2, u3)
    }
    // row1 remainder
    for (; j1 + 16 <= e1; j1 += 16) {
        unsigned c[4];
#pragma unroll
        for (int g = 0; g < 4; ++g)
            c[g] = __builtin_nontemporal_load(epk + j1 + g * 4 + slot);
        GG(c[0], p0, p1, p2, p3)
        GG(c[1], q0, q1, q2, q3)
        GG(c[2], p0, p1, p2, p3)
        GG(c[3], q0, q1, q2, q3)
    }
    for (; j1 + 4 <= e1; j1 += 4) {
        unsigned cc = __builtin_nontemporal_load(epk + j1 + slot);
        GG(cc, p0, p1, p2, p3)
    }
    if (j1 < e1) {
        int idx = j1 + slot;
        unsigned cc = (idx < e1) ? epk[idx] : 0u;
        GG(cc, q0, q1, q2, q3)
    }
    t0 += u0; t1 += u1; t2 += u2; t3 += u3;
    p0 += q0; p1 += q1; p2 += q2; p3 += q3;
    // residual reads issue here; latency hides under the shuffle reduce.
    // (ext_vector f32x4, NOT float4: NT builtins reject HIP_vector_type.)
    f32x4 ra0 = 0, rb0 = 0, ra1 = 0, rb1 = 0;
    if (L3) {
        ra0 = __builtin_nontemporal_load(
            (const f32x4*)(xa + (size_t)r0 * 64) + dim4);
        rb0 = __builtin_nontemporal_load(
            (const f32x4*)(xb + (size_t)r0 * 64) + dim4);
        if (has1) {
            ra1 = __builtin_nontemporal_load(
                (const f32x4*)(xa + (size_t)(r0 + 1) * 64) + dim4);
            rb1 = __builtin_nontemporal_load(
                (const f32x4*)(xb + (size_t)(r0 + 1) * 64) + dim4);
        }
    }
    // fold the 4 slots
    t0 += __shfl_xor(t0, 16, 64); t1 += __shfl_xor(t1, 16, 64);
    t2 += __shfl_xor(t2, 16, 64); t3 += __shfl_xor(t3, 16, 64);
    p0 += __shfl_xor(p0, 16, 64); p1 += __shfl_xor(p1, 16, 64);
    p2 += __shfl_xor(p2, 16, 64); p3 += __shfl_xor(p3, 16, 64);
    t0 += __shfl_xor(t0, 32, 64); t1 += __shfl_xor(t1, 32, 64);
    t2 += __shfl_xor(t2, 32, 64); t3 += __shfl_xor(t3, 32, 64);
    p0 += __shfl_xor(p0, 32, 64); p1 += __shfl_xor(p1, 32, 64);
    p2 += __shfl_xor(p2, 32, 64); p3 += __shfl_xor(p3, 32, 64);
    if (slot == 0) {  // 16 lanes cover the 64 dims, f32x4 each
        f32x4 bv = ((const f32x4*)bias)[dim4];
        f32x4 o;
        o.x = fmaxf(fmaf(t0, 0.0625f, bv.x), 0.f);
        o.y = fmaxf(fmaf(t1, 0.0625f, bv.y), 0.f);
        o.z = fmaxf(fmaf(t2, 0.0625f, bv.z), 0.f);
        o.w = fmaxf(fmaf(t3, 0.0625f, bv.w), 0.f);
        if (L3) o += ra0 + rb0;
        ((f32x4*)(xout + (size_t)r0 * 64))[dim4] = o;
        if (has1) {
            f32x4 o1;
            o1.x = fmaxf(fmaf(p0, 0.0625f, bv.x), 0.f);
            o1.y = fmaxf(fmaf(p1, 0.0625f, bv.y), 0.f);
            o1.z = fmaxf(fmaf(p2, 0.0625f, bv.z), 0.f);
            o1.w = fmaxf(fmaf(p3, 0.0625f, bv.w), 0.f);
            if (L3) o1 += ra1 + rb1;
            ((f32x4*)(xout + (size_t)(r0 + 1) * 64))[dim4] = o1;
        }
    }
}

// Pool: batch sorted -> run-length accumulate 64 nodes per wave, one
// atomicAdd per segment boundary per lane. h already = x1+x2+x3.
__global__ void pool_k(const float* __restrict__ h, const int* __restrict__ batch,
                       float* __restrict__ sums, int* __restrict__ cnts, int n) {
    int lane = threadIdx.x & 63;
    int w = (blockIdx.x * blockDim.x + threadIdx.x) >> 6;
    int node0 = w * 64;
    if (node0 >= n) return;
    int cur = batch[node0];
    float acc = 0.f;
    int cnt = 0;
    int end = min(node0 + 64, n);
    for (int nd = node0; nd < end; ++nd) {
        int bg = batch[nd];  // wave-uniform
        if (bg != cur) {
            atomicAdd(&sums[(size_t)cur * 64 + lane], acc);
            if (lane == 0) atomicAdd(&cnts[cur], cnt);
            acc = 0.f;
            cnt = 0;
            cur = bg;
        }
        acc += h[(size_t)nd * 64 + lane];
        cnt++;
    }
    atomicAdd(&sums[(size_t)cur * 64 + lane], acc);
    if (lane == 0) atomicAdd(&cnts[cur], cnt);
}

// Head: pooled = sums/(3*cnt); out = softmax(pooled @ Wl + bl). Wave per graph.
__global__ void final_k(const float* __restrict__ sums, const int* __restrict__ cnts,
                        const float* __restrict__ Wl, const float* __restrict__ bl,
                        float* __restrict__ out, int G) {
    int lane = threadIdx.x & 63;
    int g = (blockIdx.x * blockDim.x + threadIdx.x) >> 6;
    if (g >= G) return;
    float c = (float)max(cnts[g], 1);
    float s = sums[(size_t)g * 64 + lane] / (3.f * c);
    float y = (lane < 10) ? bl[lane] : -1e30f;
    for (int k = 0; k < 64; ++k) {
        float sk = __shfl(s, k, 64);
        if (lane < 10) y = fmaf(sk, Wl[k * 10 + lane], y);
    }
    float m = y;
#pragma unroll
    for (int off = 8; off; off >>= 1) m = fmaxf(m, __shfl_xor(m, off, 16));
    float ey = (lane < 10) ? __expf(y - m) : 0.f;
    float sm = ey;
#pragma unroll
    for (int off = 8; off; off >>= 1) sm += __shfl_xor(sm, off, 16);
    if (lane < 10) out[(size_t)g * 10 + lane] = ey / sm;
}

extern "C" void kernel_launch(void* const* d_in, const int* in_sizes, int n_in,
                              void* d_out, int out_size, void* d_ws, size_t ws_size,
                              hipStream_t stream) {
    const float* x = (const float*)d_in[0];
    const int* rows = (const int*)d_in[1];
    const int* cols = (const int*)d_in[2];
    const float* vals = (const float*)d_in[3];
    const int* batch = (const int*)d_in[4];
    const float* W1 = (const float*)d_in[5];
    const float* b1 = (const float*)d_in[6];
    const float* W2 = (const float*)d_in[7];
    const float* b2 = (const float*)d_in[8];
    const float* W3 = (const float*)d_in[9];
    const float* b3 = (const float*)d_in[10];
    const float* Wl = (const float*)d_in[11];
    const float* bl = (const float*)d_in[12];
    float* out = (float*)d_out;

    const int N = in_sizes[4];   // n_nodes (<= 131072)
    const int E = in_sizes[1];   // n_edges
    const int G = out_size / 10; // n_graphs
    const int K = (N + BROWS - 1) >> BSHIFT;

    char* p = (char*)d_ws;
    size_t off = 0;
    auto alloc = [&](size_t bytes) -> void* {
        off = (off + 255) & ~(size_t)255;
        void* r = (void*)(p + off);
        off += bytes;
        return r;
    };
    size_t featF = (size_t)N * 64 * 4;
    int* bhist = (int*)alloc(MAXK * 4);
    int* bstart = (int*)alloc((MAXK + 1) * 4);
    int* bcur = (int*)alloc(MAXK * 16 * 4);
    int* rp = (int*)alloc((size_t)(N + 2) * 4);
    // pk (bucketed, pre-sort) is dead after sort_k; alias with h (written
    // only by the layer-3 spmm, far after sort_k).
    void* regP = alloc((size_t)E * 8 > featF ? (size_t)E * 8 : featF);
    unsigned* epk = (unsigned*)alloc((size_t)E * 4);  // packed sorted edges
    unsigned char* ZqA = (unsigned char*)alloc((size_t)N * 64);
    unsigned char* ZqB = (unsigned char*)alloc((size_t)N * 64);
    float* x1 = (float*)alloc(featF);
    float* x2 = (float*)alloc(featF);
    float* sums = (float*)alloc((size_t)G * 64 * 4);
    int* cnts = (int*)alloc((size_t)G * 4);

    unsigned long long* pk = (unsigned long long*)regP;
    float* h = (float*)regP;

    (void)hipMemsetAsync(bhist, 0, MAXK * 4, stream);

    int cb = (E + CHUNK - 1) / CHUNK;
    bhist_k<<<cb, 512, 0, stream>>>(rows, bhist, E);
    bscan_k<<<1, MAXK, 0, stream>>>(bhist, bstart, bcur, rp, sums, cnts, K, E, N, G);
    binpass_k<<<cb, 512, 0, stream>>>(rows, cols, vals, bcur, pk, E);
    sort_k<<<K, 512, 0, stream>>>(bstart, pk, rp, epk, N);

    int rb = (N + 3) / 4;            // wave-per-row blocks (dense5)
    int nw2 = (N + 1) / 2;           // spmm waves (2 rows each)
    int sb = (nw2 + 3) / 4;          // spmm blocks
    dense5_k<<<rb, 256, 0, stream>>>(x, W1, ZqA, N);
    spmm2_k<0><<<sb, 256, 0, stream>>>(rp, epk, ZqA, b1, nullptr, nullptr, x1, N);
    dense64_k<<<1024, 256, 0, stream>>>(x1, W2, ZqB, N);
    spmm2_k<0><<<sb, 256, 0, stream>>>(rp, epk, ZqB, b2, nullptr, nullptr, x2, N);
    dense64_k<<<1024, 256, 0, stream>>>(x2, W3, ZqA, N);
    spmm2_k<1><<<sb, 256, 0, stream>>>(rp, epk, ZqA, b3, x1, x2, h, N);

    int pw = (N + 63) / 64;
    pool_k<<<(pw + 3) / 4, 256, 0, stream>>>(h, batch, sums, cnts, N);
    final_k<<<(G + 3) / 4, 256, 0, stream>>>(sums, cnts, Wl, bl, out, G);
}

// Round 4
// 479.495 us; speedup vs baseline: 1.3571x; 1.1166x over previous
//
#include <hip/hip_runtime.h>

// GCN3: 3x (COO spmm -> Linear(64) -> ReLU), segment-mean pool, softmax head.
// relu(spmm(X)@W + b) == relu(spmm(X@W) + b): dense transform first, then
// PULL-spmm from fp8 Z (e4m3, 64B/row). Edge records 4B: (col<<8)|fp8(val*16).
// spmm v4: wave = 16 edge-slots x 4 dim-lanes, dwordx4 gathers -> ONE gather
// instruction = 16 Zq lines in flight (v1/v3 dword gathers: 4). 32-edge body
// = 2 c-loads + 2 gathers, loads hoisted above all FMAs; tail is a single
// PREDICATED 32-edge body (clamped index, v masked to 0) so a deg<=32 row
// issues all its traffic in one burst -- no serial 4-edge dribble (was ~half
// the edges at 1 line in flight). 16 acc/lane reduced by recursive halving
// with dim-splitting (15 shfl vs 128-op naive); final lane<->dim bit-permuted
// so epilogue is all-lane. launch_bounds(256,8) caps VGPR at 64 = full occ.
// Evidence: v3 null (2-row ILP, same total MLP) => limit is total lines in
// flight chip-wide; this raises per-wave MLP 4x without cutting wave count.
// dense64: W column in 64 VGPRs/lane (launch_bounds(256,1)).
// CSR build: LDS-staged binpass into 512-row buckets, per-bucket counting sort.

#define BSHIFT 9
#define BROWS  (1 << BSHIFT)   // 512 rows per bucket
#define MAXK   256             // supports N <= 131072
#define CHUNK  6144            // edges per binpass/bhist block

typedef float f32x4 __attribute__((ext_vector_type(4)));
typedef unsigned u32x4 __attribute__((ext_vector_type(4)));

__device__ inline unsigned char f2q(float f) {  // fp8 e4m3 RNE (saturating)
    unsigned p = __builtin_amdgcn_cvt_pk_fp8_f32(f, f, 0u, false);
    return (unsigned char)(p & 0xffu);
}
template <int SEL>
__device__ inline float q2f(unsigned q) {  // byte-select fp8->f32 (SEL = ICE)
    return __builtin_amdgcn_cvt_f32_fp8(q, SEL);
}

// Per-block LDS histogram of bucket ids -> global bucket counts.
__global__ __launch_bounds__(512) void bhist_k(const int* __restrict__ rows,
                                               int* __restrict__ bhist, int E) {
    __shared__ int h[MAXK];
    int tx = threadIdx.x;
    if (tx < MAXK) h[tx] = 0;
    __syncthreads();
    int e0 = blockIdx.x * CHUNK, ee = min(e0 + CHUNK, E);
    for (int e = e0 + tx; e < ee; e += 512)
        atomicAdd(&h[rows[e] >> BSHIFT], 1);
    __syncthreads();
    if (tx < MAXK && h[tx]) atomicAdd(&bhist[tx], h[tx]);
}

// Exclusive scan of bucket counts (single block); init padded cursors; rp[N]=E.
// Also zeroes the pool buffers (sums/cnts) so those memset dispatches go away.
__global__ __launch_bounds__(MAXK) void bscan_k(const int* __restrict__ bhist,
                                                int* __restrict__ bstart,
                                                int* __restrict__ bcur,
                                                int* __restrict__ rp,
                                                float* __restrict__ sums,
                                                int* __restrict__ cnts,
                                                int K, int E, int N, int G) {
    __shared__ int s[MAXK];
    int tx = threadIdx.x;
    f32x4* s4 = (f32x4*)sums;
    for (int i = tx; i < G * 16; i += MAXK) s4[i] = 0;
    for (int i = tx; i < G; i += MAXK) cnts[i] = 0;
    int v = (tx < K) ? bhist[tx] : 0;
    s[tx] = v;
    __syncthreads();
    for (int off = 1; off < MAXK; off <<= 1) {
        int t = (tx >= off) ? s[tx - off] : 0;
        __syncthreads();
        s[tx] += t;
        __syncthreads();
    }
    if (tx < K) {
        bstart[tx] = s[tx] - v;
        bcur[tx * 16] = s[tx] - v;  // 1 cursor per 64B line
    }
    if (tx == K - 1) bstart[K] = E;
    if (tx == 0) rp[N] = E;
}

// Bin edges by 512-row bucket, staged in LDS so global writes are ~31-edge
// single-CU bursts. Record (u64): lo32=(col<<9)|(row&511), hi32=val bits.
__global__ __launch_bounds__(512) void binpass_k(
    const int* __restrict__ rows, const int* __restrict__ cols,
    const float* __restrict__ vals, int* __restrict__ bcur,
    unsigned long long* __restrict__ pk, int E) {
    __shared__ int h[MAXK], base[MAXK], gbase[MAXK], lcnt[MAXK];
    __shared__ unsigned long long st[CHUNK];  // 48 KB
    int tx = threadIdx.x;
    if (tx < MAXK) h[tx] = 0;
    __syncthreads();
    int e0 = blockIdx.x * CHUNK, ee = min(e0 + CHUNK, E);
    for (int e = e0 + tx; e < ee; e += 512)
        atomicAdd(&h[rows[e] >> BSHIFT], 1);
    __syncthreads();
    int v = (tx < MAXK) ? h[tx] : 0;
    if (tx < MAXK) lcnt[tx] = v;  // scan buffer
    __syncthreads();
    for (int off = 1; off < MAXK; off <<= 1) {
        int t = (tx >= off && tx < MAXK) ? lcnt[tx - off] : 0;
        __syncthreads();
        if (tx < MAXK) lcnt[tx] += t;
        __syncthreads();
    }
    if (tx < MAXK) {
        base[tx] = lcnt[tx] - v;
        if (v) gbase[tx] = atomicAdd(&bcur[tx * 16], v);
        lcnt[tx] = 0;
    }
    __syncthreads();
    for (int e = e0 + tx; e < ee; e += 512) {
        int r = rows[e];
        int c = cols[e];
        float vv = vals[e];
        int b = r >> BSHIFT;
        int p = base[b] + atomicAdd(&lcnt[b], 1);
        unsigned lo = ((unsigned)c << BSHIFT) | (unsigned)(r & (BROWS - 1));
        st[p] = (unsigned long long)lo
              | ((unsigned long long)(unsigned)__float_as_int(vv) << 32);
    }
    __syncthreads();
    // flush contiguous per-bucket runs, wave-parallel. NT safe: 64 lanes x 8B
    // = 512B contiguous per instruction (full lines covered).
    int lane = tx & 63, wid = tx >> 6;
    for (int b = wid; b < MAXK; b += 8) {
        int cnt = h[b];
        if (!cnt) continue;
        int lb = base[b], gb = gbase[b];
        for (int i = lane; i < cnt; i += 64)
            __builtin_nontemporal_store(st[lb + i], &pk[gb + i]);
    }
}

// Per-bucket counting sort: one block per bucket. LDS hist over 512 rows,
// scan -> rp, then local scatter into the bucket's contiguous epk window.
// CACHED loads/stores (sub-line scatter: L2 must assemble the lines).
// Output record (4B): (col << 8) | fp8(val * 16).
__global__ __launch_bounds__(512) void sort_k(
    const int* __restrict__ bstart, const unsigned long long* __restrict__ pk,
    int* __restrict__ rp, unsigned* __restrict__ epk, int n) {
    __shared__ int hist[BROWS], cur[BROWS];
    int tx = threadIdx.x;
    int b = blockIdx.x;
    int row0 = b << BSHIFT;
    int s = bstart[b], e = bstart[b + 1];
    hist[tx] = 0;
    __syncthreads();
    for (int j = s + tx; j < e; j += 512) {
        unsigned lo = (unsigned)pk[j];
        atomicAdd(&hist[lo & (BROWS - 1)], 1);
    }
    __syncthreads();
    int v = hist[tx];
    for (int off = 1; off < BROWS; off <<= 1) {
        int t = (tx >= off) ? hist[tx - off] : 0;
        __syncthreads();
        hist[tx] += t;
        __syncthreads();
    }
    int excl = hist[tx] - v;
    cur[tx] = excl;
    if (row0 + tx < n) rp[row0 + tx] = s + excl;
    __syncthreads();
    for (int j = s + tx; j < e; j += 512) {
        unsigned long long rec = pk[j];
        unsigned lo = (unsigned)rec;
        float vv = __int_as_float((int)(unsigned)(rec >> 32));
        int r = (int)(lo & (BROWS - 1));
        int q = atomicAdd(&cur[r], 1);
        epk[s + q] = ((lo >> BSHIFT) << 8) | (unsigned)f2q(vv * 16.f);
    }
}

// Zq = fp8(X @ W1), X:[n,5]. Wave per row, lane = out dim.
__global__ __launch_bounds__(256) void dense5_k(
    const float* __restrict__ X, const float* __restrict__ W,
    unsigned char* __restrict__ Zq, int n) {
    int lane = threadIdx.x & 63;
    int row = (blockIdx.x * blockDim.x + threadIdx.x) >> 6;
    if (row >= n) return;
    float w0 = W[lane], w1 = W[64 + lane], w2 = W[128 + lane],
          w3 = W[192 + lane], w4 = W[256 + lane];
    float xv = (lane < 5) ? X[(size_t)row * 5 + lane] : 0.f;
    float y = __shfl(xv, 0, 64) * w0;
    y = fmaf(__shfl(xv, 1, 64), w1, y);
    y = fmaf(__shfl(xv, 2, 64), w2, y);
    y = fmaf(__shfl(xv, 3, 64), w3, y);
    y = fmaf(__shfl(xv, 4, 64), w4, y);
    Zq[(size_t)row * 64 + lane] = f2q(y);
}

// Zq = fp8(X @ W): W column `lane` in 64 VGPRs. launch_bounds(256,1) lets the
// allocator keep all 64 live. Grid 1024 blocks = 16 waves/CU; ~24 rows/wave
// amortizes the W load. Per row: 16 wave-uniform float4 loads + 64 fmaf.
__global__ __launch_bounds__(256, 1) void dense64_k(
    const float* __restrict__ X, const float* __restrict__ W,
    unsigned char* __restrict__ Zq, int n) {
    int lane = threadIdx.x & 63, wid = threadIdx.x >> 6;
    float wr[64];
#pragma unroll
    for (int k = 0; k < 64; ++k) wr[k] = W[k * 64 + lane];
    int wave = blockIdx.x * 4 + wid;
    int nw = gridDim.x * 4;
    for (int row = wave; row < n; row += nw) {
        const f32x4* xr = (const f32x4*)(X + (size_t)row * 64);
        float y = 0.f;
#pragma unroll
        for (int k4 = 0; k4 < 16; ++k4) {
            f32x4 xv = xr[k4];  // wave-uniform broadcast
            y = fmaf(xv.x, wr[k4 * 4 + 0], y);
            y = fmaf(xv.y, wr[k4 * 4 + 1], y);
            y = fmaf(xv.z, wr[k4 * 4 + 2], y);
            y = fmaf(xv.w, wr[k4 * 4 + 3], y);
        }
        Zq[(size_t)row * 64 + lane] = f2q(y);
    }
}

// 16 FMAs of one edge's 16B Zq chunk into a[0..15] (dims dim4*16 + 0..15).
#define FMA16(v, d)                                                            \
    a[0]  = fmaf(v, q2f<0>((d).x), a[0]);                                      \
    a[1]  = fmaf(v, q2f<1>((d).x), a[1]);                                      \
    a[2]  = fmaf(v, q2f<2>((d).x), a[2]);                                      \
    a[3]  = fmaf(v, q2f<3>((d).x), a[3]);                                      \
    a[4]  = fmaf(v, q2f<0>((d).y), a[4]);                                      \
    a[5]  = fmaf(v, q2f<1>((d).y), a[5]);                                      \
    a[6]  = fmaf(v, q2f<2>((d).y), a[6]);                                      \
    a[7]  = fmaf(v, q2f<3>((d).y), a[7]);                                      \
    a[8]  = fmaf(v, q2f<0>((d).z), a[8]);                                      \
    a[9]  = fmaf(v, q2f<1>((d).z), a[9]);                                      \
    a[10] = fmaf(v, q2f<2>((d).z), a[10]);                                     \
    a[11] = fmaf(v, q2f<3>((d).z), a[11]);                                     \
    a[12] = fmaf(v, q2f<0>((d).w), a[12]);                                     \
    a[13] = fmaf(v, q2f<1>((d).w), a[13]);                                     \
    a[14] = fmaf(v, q2f<2>((d).w), a[14]);                                     \
    a[15] = fmaf(v, q2f<3>((d).w), a[15]);

// spmm v4: wave per row; 16 edge-slots (lane>>2) x 4 dim-lanes (lane&3).
// One dwordx4 gather = 16 lines in flight. Predicated tail body (clamped
// index, v masked 0; Zq is NaN-free since cvt_pk_fp8_f32 saturates).
template <int L3>
__global__ __launch_bounds__(256, 8) void spmm16_k(
    const int* __restrict__ rp, const unsigned* __restrict__ epk,
    const unsigned char* __restrict__ Zq, const float* __restrict__ bias,
    const float* __restrict__ xa, const float* __restrict__ xb,
    float* __restrict__ xout, int n) {
    int lane = threadIdx.x & 63;
    int dim4 = lane & 3, slot = lane >> 2;
    int row = (int)((blockIdx.x * blockDim.x + threadIdx.x) >> 6);
    if (row >= n) return;
    // final lane<->dim mapping after the dim-splitting reduce (bit-permuted)
    int dimL = dim4 * 16 + ((lane >> 2) & 1) * 8 + ((lane >> 3) & 1) * 4 +
               ((lane >> 4) & 1) * 2 + ((lane >> 5) & 1);
    float bv = bias[dimL];  // preload, hides under the gather chain
    const unsigned char* zb = Zq + (dim4 << 4);
    int s = rp[row], e = rp[row + 1];

    float a[16];
#pragma unroll
    for (int k = 0; k < 16; ++k) a[k] = 0.f;

    int j = s;
    for (; j + 32 <= e; j += 32) {  // 2 c-loads + 2 gathers, loads first
        unsigned c0 = __builtin_nontemporal_load(epk + j + slot);
        unsigned c1 = __builtin_nontemporal_load(epk + j + 16 + slot);
        u32x4 d0 = *(const u32x4*)(zb + ((c0 >> 8) << 6));
        u32x4 d1 = *(const u32x4*)(zb + ((c1 >> 8) << 6));
        float v0 = q2f<0>(c0);
        float v1 = q2f<0>(c1);
        FMA16(v0, d0)
        FMA16(v1, d1)
    }
    if (j < e) {  // predicated 32-edge body: whole remainder in one burst
        int i0 = min(j + slot, e - 1);
        int i1 = min(j + 16 + slot, e - 1);
        unsigned c0 = __builtin_nontemporal_load(epk + i0);
        unsigned c1 = __builtin_nontemporal_load(epk + i1);
        u32x4 d0 = *(const u32x4*)(zb + ((c0 >> 8) << 6));
        u32x4 d1 = *(const u32x4*)(zb + ((c1 >> 8) << 6));
        float v0 = (j + slot < e) ? q2f<0>(c0) : 0.f;
        float v1 = (j + 16 + slot < e) ? q2f<0>(c1) : 0.f;
        FMA16(v0, d0)
        FMA16(v1, d1)
    }

    // residual reads issue before the reduce; latency hides under shuffles
    float ra = 0.f, rb = 0.f;
    if (L3) {
        ra = __builtin_nontemporal_load(xa + (size_t)row * 64 + dimL);
        rb = __builtin_nontemporal_load(xb + (size_t)row * 64 + dimL);
    }

    // recursive-halving reduce over 16 slots with dim-splitting:
    // each round keep half the dims, donate the other half to the partner.
    float r8[8];
    {
        bool h = (lane & 4) != 0;
#pragma unroll
        for (int k = 0; k < 8; ++k) {
            float keep = h ? a[8 + k] : a[k];
            float give = h ? a[k] : a[8 + k];
            r8[k] = keep + __shfl_xor(give, 4, 64);
        }
    }
    float r4[4];
    {
        bool h = (lane & 8) != 0;
#pragma unroll
        for (int k = 0; k < 4; ++k) {
            float keep = h ? r8[4 + k] : r8[k];
            float give = h ? r8[k] : r8[4 + k];
            r4[k] = keep + __shfl_xor(give, 8, 64);
        }
    }
    float r2[2];
    {
        bool h = (lane & 16) != 0;
#pragma unroll
        for (int k = 0; k < 2; ++k) {
            float keep = h ? r4[2 + k] : r4[k];
            float give = h ? r4[k] : r4[2 + k];
            r2[k] = keep + __shfl_xor(give, 16, 64);
        }
    }
    float tot;
    {
        bool h = (lane & 32) != 0;
        float keep = h ? r2[1] : r2[0];
        float give = h ? r2[0] : r2[1];
        tot = keep + __shfl_xor(give, 32, 64);
    }

    float o = fmaxf(fmaf(tot, 0.0625f, bv), 0.f);
    if (L3) o += ra + rb;
    xout[(size_t)row * 64 + dimL] = o;  // all 64 lanes store (256B/row)
}

// Pool: batch sorted -> run-length accumulate 64 nodes per wave, one
// atomicAdd per segment boundary per lane. h already = x1+x2+x3.
__global__ void pool_k(const float* __restrict__ h, const int* __restrict__ batch,
                       float* __restrict__ sums, int* __restrict__ cnts, int n) {
    int lane = threadIdx.x & 63;
    int w = (blockIdx.x * blockDim.x + threadIdx.x) >> 6;
    int node0 = w * 64;
    if (node0 >= n) return;
    int cur = batch[node0];
    float acc = 0.f;
    int cnt = 0;
    int end = min(node0 + 64, n);
    for (int nd = node0; nd < end; ++nd) {
        int bg = batch[nd];  // wave-uniform
        if (bg != cur) {
            atomicAdd(&sums[(size_t)cur * 64 + lane], acc);
            if (lane == 0) atomicAdd(&cnts[cur], cnt);
            acc = 0.f;
            cnt = 0;
            cur = bg;
        }
        acc += h[(size_t)nd * 64 + lane];
        cnt++;
    }
    atomicAdd(&sums[(size_t)cur * 64 + lane], acc);
    if (lane == 0) atomicAdd(&cnts[cur], cnt);
}

// Head: pooled = sums/(3*cnt); out = softmax(pooled @ Wl + bl). Wave per graph.
__global__ void final_k(const float* __restrict__ sums, const int* __restrict__ cnts,
                        const float* __restrict__ Wl, const float* __restrict__ bl,
                        float* __restrict__ out, int G) {
    int lane = threadIdx.x & 63;
    int g = (blockIdx.x * blockDim.x + threadIdx.x) >> 6;
    if (g >= G) return;
    float c = (float)max(cnts[g], 1);
    float s = sums[(size_t)g * 64 + lane] / (3.f * c);
    float y = (lane < 10) ? bl[lane] : -1e30f;
    for (int k = 0; k < 64; ++k) {
        float sk = __shfl(s, k, 64);
        if (lane < 10) y = fmaf(sk, Wl[k * 10 + lane], y);
    }
    float m = y;
#pragma unroll
    for (int off = 8; off; off >>= 1) m = fmaxf(m, __shfl_xor(m, off, 16));
    float ey = (lane < 10) ? __expf(y - m) : 0.f;
    float sm = ey;
#pragma unroll
    for (int off = 8; off; off >>= 1) sm += __shfl_xor(sm, off, 16);
    if (lane < 10) out[(size_t)g * 10 + lane] = ey / sm;
}

extern "C" void kernel_launch(void* const* d_in, const int* in_sizes, int n_in,
                              void* d_out, int out_size, void* d_ws, size_t ws_size,
                              hipStream_t stream) {
    const float* x = (const float*)d_in[0];
    const int* rows = (const int*)d_in[1];
    const int* cols = (const int*)d_in[2];
    const float* vals = (const float*)d_in[3];
    const int* batch = (const int*)d_in[4];
    const float* W1 = (const float*)d_in[5];
    const float* b1 = (const float*)d_in[6];
    const float* W2 = (const float*)d_in[7];
    const float* b2 = (const float*)d_in[8];
    const float* W3 = (const float*)d_in[9];
    const float* b3 = (const float*)d_in[10];
    const float* Wl = (const float*)d_in[11];
    const float* bl = (const float*)d_in[12];
    float* out = (float*)d_out;

    const int N = in_sizes[4];   // n_nodes (<= 131072)
    const int E = in_sizes[1];   // n_edges
    const int G = out_size / 10; // n_graphs
    const int K = (N + BROWS - 1) >> BSHIFT;

    char* p = (char*)d_ws;
    size_t off = 0;
    auto alloc = [&](size_t bytes) -> void* {
        off = (off + 255) & ~(size_t)255;
        void* r = (void*)(p + off);
        off += bytes;
        return r;
    };
    size_t featF = (size_t)N * 64 * 4;
    int* bhist = (int*)alloc(MAXK * 4);
    int* bstart = (int*)alloc((MAXK + 1) * 4);
    int* bcur = (int*)alloc(MAXK * 16 * 4);
    int* rp = (int*)alloc((size_t)(N + 2) * 4);
    // pk (bucketed, pre-sort) is dead after sort_k; alias with h (written
    // only by the layer-3 spmm, far after sort_k).
    void* regP = alloc((size_t)E * 8 > featF ? (size_t)E * 8 : featF);
    unsigned* epk = (unsigned*)alloc((size_t)E * 4);  // packed sorted edges
    unsigned char* ZqA = (unsigned char*)alloc((size_t)N * 64);
    unsigned char* ZqB = (unsigned char*)alloc((size_t)N * 64);
    float* x1 = (float*)alloc(featF);
    float* x2 = (float*)alloc(featF);
    float* sums = (float*)alloc((size_t)G * 64 * 4);
    int* cnts = (int*)alloc((size_t)G * 4);

    unsigned long long* pk = (unsigned long long*)regP;
    float* h = (float*)regP;

    (void)hipMemsetAsync(bhist, 0, MAXK * 4, stream);

    int cb = (E + CHUNK - 1) / CHUNK;
    bhist_k<<<cb, 512, 0, stream>>>(rows, bhist, E);
    bscan_k<<<1, MAXK, 0, stream>>>(bhist, bstart, bcur, rp, sums, cnts, K, E, N, G);
    binpass_k<<<cb, 512, 0, stream>>>(rows, cols, vals, bcur, pk, E);
    sort_k<<<K, 512, 0, stream>>>(bstart, pk, rp, epk, N);

    int rb = (N + 3) / 4;  // wave-per-row blocks
    dense5_k<<<rb, 256, 0, stream>>>(x, W1, ZqA, N);
    spmm16_k<0><<<rb, 256, 0, stream>>>(rp, epk, ZqA, b1, nullptr, nullptr, x1, N);
    dense64_k<<<1024, 256, 0, stream>>>(x1, W2, ZqB, N);
    spmm16_k<0><<<rb, 256, 0, stream>>>(rp, epk, ZqB, b2, nullptr, nullptr, x2, N);
    dense64_k<<<1024, 256, 0, stream>>>(x2, W3, ZqA, N);
    spmm16_k<1><<<rb, 256, 0, stream>>>(rp, epk, ZqA, b3, x1, x2, h, N);

    int pw = (N + 63) / 64;
    pool_k<<<(pw + 3) / 4, 256, 0, stream>>>(h, batch, sums, cnts, N);
    final_k<<<(G + 3) / 4, 256, 0, stream>>>(sums, cnts, Wl, bl, out, G);
}

// Round 5
// 392.006 us; speedup vs baseline: 1.6600x; 1.2232x over previous
//
#include <hip/hip_runtime.h>

// GCN3: 3x (COO spmm -> Linear(64) -> ReLU), segment-mean pool, softmax head.
// relu(spmm(X)@W + b) == relu(spmm(X@W) + b): dense transform first, then
// PULL-spmm from fp8 Z (e4m3, 64B/row). Edge records 4B: (col<<8)|fp8(val*16).
// spmm v4: wave = 16 edge-slots x 4 dim-lanes, dwordx4 gathers -> ONE gather
// instruction = 16 Zq lines in flight. 32-edge body = 2 c-loads + 2 gathers;
// tail is a single PREDICATED 32-edge body. 16 acc/lane reduced by recursive
// halving with dim-splitting; final lane<->dim bit-permuted.
// dense64 v5: MFMA (16x16x32 bf16). Old VALU version regressed to VGPR=40
// (W reloaded per row) -> 58us at 4% HBM. Wave = 16-row tile; 8 B-fragments
// (4 col-tiles x 2 K-halves) cvt_pk'd from W once per wave; per tile 4
// f32x4 A-loads + 8 MFMA + 16 fp8 byte stores. bf16 RNE error is 32x below
// the fp8 quantization applied to the same values.
// A[l&15][8*(l>>4)+i], B[8*(l>>4)+i][l&15], D col=l&15 row=4*(l>>4)+reg.
// CSR build: LDS-staged binpass into 512-row buckets, per-bucket counting sort.

#define BSHIFT 9
#define BROWS  (1 << BSHIFT)   // 512 rows per bucket
#define MAXK   256             // supports N <= 131072
#define CHUNK  6144            // edges per binpass/bhist block

typedef float f32x4 __attribute__((ext_vector_type(4)));
typedef unsigned u32x4 __attribute__((ext_vector_type(4)));
typedef short bf16x8 __attribute__((ext_vector_type(8)));

__device__ inline unsigned char f2q(float f) {  // fp8 e4m3 RNE (saturating)
    unsigned p = __builtin_amdgcn_cvt_pk_fp8_f32(f, f, 0u, false);
    return (unsigned char)(p & 0xffu);
}
template <int SEL>
__device__ inline float q2f(unsigned q) {  // byte-select fp8->f32 (SEL = ICE)
    return __builtin_amdgcn_cvt_f32_fp8(q, SEL);
}

// pack 8 f32 (k ascending: lo.x..lo.w, hi.x..hi.w) -> bf16x8, RNE
__device__ inline bf16x8 pack_bf8(f32x4 lo, f32x4 hi) {
    union { u32x4 u; bf16x8 h; } r;
    asm("v_cvt_pk_bf16_f32 %0, %1, %2" : "=v"(r.u.x) : "v"(lo.x), "v"(lo.y));
    asm("v_cvt_pk_bf16_f32 %0, %1, %2" : "=v"(r.u.y) : "v"(lo.z), "v"(lo.w));
    asm("v_cvt_pk_bf16_f32 %0, %1, %2" : "=v"(r.u.z) : "v"(hi.x), "v"(hi.y));
    asm("v_cvt_pk_bf16_f32 %0, %1, %2" : "=v"(r.u.w) : "v"(hi.z), "v"(hi.w));
    return r.h;
}

// Per-block LDS histogram of bucket ids -> global bucket counts.
__global__ __launch_bounds__(512) void bhist_k(const int* __restrict__ rows,
                                               int* __restrict__ bhist, int E) {
    __shared__ int h[MAXK];
    int tx = threadIdx.x;
    if (tx < MAXK) h[tx] = 0;
    __syncthreads();
    int e0 = blockIdx.x * CHUNK, ee = min(e0 + CHUNK, E);
    for (int e = e0 + tx; e < ee; e += 512)
        atomicAdd(&h[rows[e] >> BSHIFT], 1);
    __syncthreads();
    if (tx < MAXK && h[tx]) atomicAdd(&bhist[tx], h[tx]);
}

// Exclusive scan of bucket counts (single block); init padded cursors; rp[N]=E.
// Also zeroes the pool buffers (sums/cnts) so those memset dispatches go away.
__global__ __launch_bounds__(MAXK) void bscan_k(const int* __restrict__ bhist,
                                                int* __restrict__ bstart,
                                                int* __restrict__ bcur,
                                                int* __restrict__ rp,
                                                float* __restrict__ sums,
                                                int* __restrict__ cnts,
                                                int K, int E, int N, int G) {
    __shared__ int s[MAXK];
    int tx = threadIdx.x;
    f32x4* s4 = (f32x4*)sums;
    for (int i = tx; i < G * 16; i += MAXK) s4[i] = 0;
    for (int i = tx; i < G; i += MAXK) cnts[i] = 0;
    int v = (tx < K) ? bhist[tx] : 0;
    s[tx] = v;
    __syncthreads();
    for (int off = 1; off < MAXK; off <<= 1) {
        int t = (tx >= off) ? s[tx - off] : 0;
        __syncthreads();
        s[tx] += t;
        __syncthreads();
    }
    if (tx < K) {
        bstart[tx] = s[tx] - v;
        bcur[tx * 16] = s[tx] - v;  // 1 cursor per 64B line
    }
    if (tx == K - 1) bstart[K] = E;
    if (tx == 0) rp[N] = E;
}

// Bin edges by 512-row bucket, staged in LDS so global writes are ~31-edge
// single-CU bursts. Record (u64): lo32=(col<<9)|(row&511), hi32=val bits.
__global__ __launch_bounds__(512) void binpass_k(
    const int* __restrict__ rows, const int* __restrict__ cols,
    const float* __restrict__ vals, int* __restrict__ bcur,
    unsigned long long* __restrict__ pk, int E) {
    __shared__ int h[MAXK], base[MAXK], gbase[MAXK], lcnt[MAXK];
    __shared__ unsigned long long st[CHUNK];  // 48 KB
    int tx = threadIdx.x;
    if (tx < MAXK) h[tx] = 0;
    __syncthreads();
    int e0 = blockIdx.x * CHUNK, ee = min(e0 + CHUNK, E);
    for (int e = e0 + tx; e < ee; e += 512)
        atomicAdd(&h[rows[e] >> BSHIFT], 1);
    __syncthreads();
    int v = (tx < MAXK) ? h[tx] : 0;
    if (tx < MAXK) lcnt[tx] = v;  // scan buffer
    __syncthreads();
    for (int off = 1; off < MAXK; off <<= 1) {
        int t = (tx >= off && tx < MAXK) ? lcnt[tx - off] : 0;
        __syncthreads();
        if (tx < MAXK) lcnt[tx] += t;
        __syncthreads();
    }
    if (tx < MAXK) {
        base[tx] = lcnt[tx] - v;
        if (v) gbase[tx] = atomicAdd(&bcur[tx * 16], v);
        lcnt[tx] = 0;
    }
    __syncthreads();
    for (int e = e0 + tx; e < ee; e += 512) {
        int r = rows[e];
        int c = cols[e];
        float vv = vals[e];
        int b = r >> BSHIFT;
        int p = base[b] + atomicAdd(&lcnt[b], 1);
        unsigned lo = ((unsigned)c << BSHIFT) | (unsigned)(r & (BROWS - 1));
        st[p] = (unsigned long long)lo
              | ((unsigned long long)(unsigned)__float_as_int(vv) << 32);
    }
    __syncthreads();
    // flush contiguous per-bucket runs, wave-parallel. NT safe: 64 lanes x 8B
    // = 512B contiguous per instruction (full lines covered).
    int lane = tx & 63, wid = tx >> 6;
    for (int b = wid; b < MAXK; b += 8) {
        int cnt = h[b];
        if (!cnt) continue;
        int lb = base[b], gb = gbase[b];
        for (int i = lane; i < cnt; i += 64)
            __builtin_nontemporal_store(st[lb + i], &pk[gb + i]);
    }
}

// Per-bucket counting sort: one block per bucket. LDS hist over 512 rows,
// scan -> rp, then local scatter into the bucket's contiguous epk window.
// CACHED loads/stores (sub-line scatter: L2 must assemble the lines).
// Output record (4B): (col << 8) | fp8(val * 16).
__global__ __launch_bounds__(512) void sort_k(
    const int* __restrict__ bstart, const unsigned long long* __restrict__ pk,
    int* __restrict__ rp, unsigned* __restrict__ epk, int n) {
    __shared__ int hist[BROWS], cur[BROWS];
    int tx = threadIdx.x;
    int b = blockIdx.x;
    int row0 = b << BSHIFT;
    int s = bstart[b], e = bstart[b + 1];
    hist[tx] = 0;
    __syncthreads();
    for (int j = s + tx; j < e; j += 512) {
        unsigned lo = (unsigned)pk[j];
        atomicAdd(&hist[lo & (BROWS - 1)], 1);
    }
    __syncthreads();
    int v = hist[tx];
    for (int off = 1; off < BROWS; off <<= 1) {
        int t = (tx >= off) ? hist[tx - off] : 0;
        __syncthreads();
        hist[tx] += t;
        __syncthreads();
    }
    int excl = hist[tx] - v;
    cur[tx] = excl;
    if (row0 + tx < n) rp[row0 + tx] = s + excl;
    __syncthreads();
    for (int j = s + tx; j < e; j += 512) {
        unsigned long long rec = pk[j];
        unsigned lo = (unsigned)rec;
        float vv = __int_as_float((int)(unsigned)(rec >> 32));
        int r = (int)(lo & (BROWS - 1));
        int q = atomicAdd(&cur[r], 1);
        epk[s + q] = ((lo >> BSHIFT) << 8) | (unsigned)f2q(vv * 16.f);
    }
}

// Zq = fp8(X @ W1), X:[n,5]. Wave per row, lane = out dim.
__global__ __launch_bounds__(256) void dense5_k(
    const float* __restrict__ X, const float* __restrict__ W,
    unsigned char* __restrict__ Zq, int n) {
    int lane = threadIdx.x & 63;
    int row = (blockIdx.x * blockDim.x + threadIdx.x) >> 6;
    if (row >= n) return;
    float w0 = W[lane], w1 = W[64 + lane], w2 = W[128 + lane],
          w3 = W[192 + lane], w4 = W[256 + lane];
    float xv = (lane < 5) ? X[(size_t)row * 5 + lane] : 0.f;
    float y = __shfl(xv, 0, 64) * w0;
    y = fmaf(__shfl(xv, 1, 64), w1, y);
    y = fmaf(__shfl(xv, 2, 64), w2, y);
    y = fmaf(__shfl(xv, 3, 64), w3, y);
    y = fmaf(__shfl(xv, 4, 64), w4, y);
    Zq[(size_t)row * 64 + lane] = f2q(y);
}

// dense64 v5: Zq = fp8(X @ W) via mfma_f32_16x16x32_bf16. Wave = 16-row
// tile x 64 cols. B (W) fragments built once per wave: frag (c,m) holds
// B[k=32m+8*(l>>4)+i][col=16c+(l&15)]. Per tile: A frags from 4 f32x4 loads
// (lane: row=l&15, k=8*(l>>4)+i (+32m)), 8 MFMAs (K-accumulate), D written
// as fp8 bytes: row=rowb+4*(l>>4)+j, col=16c+(l&15).
__global__ __launch_bounds__(256, 4) void dense64_k(
    const float* __restrict__ X, const float* __restrict__ W,
    unsigned char* __restrict__ Zq, int n) {
    int lane = threadIdx.x & 63, wid = threadIdx.x >> 6;
    int l15 = lane & 15, lk = lane >> 4;
    bf16x8 bw[4][2];
#pragma unroll
    for (int c = 0; c < 4; ++c) {
#pragma unroll
        for (int m = 0; m < 2; ++m) {
            const float* wp = W + (size_t)(32 * m + 8 * lk) * 64 + 16 * c + l15;
            f32x4 lo, hi;
            lo.x = wp[0];   lo.y = wp[64];  lo.z = wp[128]; lo.w = wp[192];
            hi.x = wp[256]; hi.y = wp[320]; hi.z = wp[384]; hi.w = wp[448];
            bw[c][m] = pack_bf8(lo, hi);
        }
    }
    int nt = (n + 15) >> 4;
    int nwv = (int)(gridDim.x * 4);
    for (int t = blockIdx.x * 4 + wid; t < nt; t += nwv) {
        int rowb = t << 4;
        int ar = min(rowb + l15, n - 1);  // clamped A row (stores guarded)
        const float* xr = X + (size_t)ar * 64 + 8 * lk;
        f32x4 a0 = *(const f32x4*)(xr);
        f32x4 a1 = *(const f32x4*)(xr + 4);
        f32x4 a2 = *(const f32x4*)(xr + 32);
        f32x4 a3 = *(const f32x4*)(xr + 36);
        bf16x8 A0 = pack_bf8(a0, a1);
        bf16x8 A1 = pack_bf8(a2, a3);
        f32x4 acc0 = 0, acc1 = 0, acc2 = 0, acc3 = 0;
        acc0 = __builtin_amdgcn_mfma_f32_16x16x32_bf16(A0, bw[0][0], acc0, 0, 0, 0);
        acc1 = __builtin_amdgcn_mfma_f32_16x16x32_bf16(A0, bw[1][0], acc1, 0, 0, 0);
        acc2 = __builtin_amdgcn_mfma_f32_16x16x32_bf16(A0, bw[2][0], acc2, 0, 0, 0);
        acc3 = __builtin_amdgcn_mfma_f32_16x16x32_bf16(A0, bw[3][0], acc3, 0, 0, 0);
        acc0 = __builtin_amdgcn_mfma_f32_16x16x32_bf16(A1, bw[0][1], acc0, 0, 0, 0);
        acc1 = __builtin_amdgcn_mfma_f32_16x16x32_bf16(A1, bw[1][1], acc1, 0, 0, 0);
        acc2 = __builtin_amdgcn_mfma_f32_16x16x32_bf16(A1, bw[2][1], acc2, 0, 0, 0);
        acc3 = __builtin_amdgcn_mfma_f32_16x16x32_bf16(A1, bw[3][1], acc3, 0, 0, 0);
#pragma unroll
        for (int j = 0; j < 4; ++j) {
            int r = rowb + 4 * lk + j;
            if (r < n) {
                unsigned char* zp = Zq + (size_t)r * 64 + l15;
                zp[0]  = f2q(acc0[j]);
                zp[16] = f2q(acc1[j]);
                zp[32] = f2q(acc2[j]);
                zp[48] = f2q(acc3[j]);
            }
        }
    }
}

// 16 FMAs of one edge's 16B Zq chunk into a[0..15] (dims dim4*16 + 0..15).
#define FMA16(v, d)                                                            \
    a[0]  = fmaf(v, q2f<0>((d).x), a[0]);                                      \
    a[1]  = fmaf(v, q2f<1>((d).x), a[1]);                                      \
    a[2]  = fmaf(v, q2f<2>((d).x), a[2]);                                      \
    a[3]  = fmaf(v, q2f<3>((d).x), a[3]);                                      \
    a[4]  = fmaf(v, q2f<0>((d).y), a[4]);                                      \
    a[5]  = fmaf(v, q2f<1>((d).y), a[5]);                                      \
    a[6]  = fmaf(v, q2f<2>((d).y), a[6]);                                      \
    a[7]  = fmaf(v, q2f<3>((d).y), a[7]);                                      \
    a[8]  = fmaf(v, q2f<0>((d).z), a[8]);                                      \
    a[9]  = fmaf(v, q2f<1>((d).z), a[9]);                                      \
    a[10] = fmaf(v, q2f<2>((d).z), a[10]);                                     \
    a[11] = fmaf(v, q2f<3>((d).z), a[11]);                                     \
    a[12] = fmaf(v, q2f<0>((d).w), a[12]);                                     \
    a[13] = fmaf(v, q2f<1>((d).w), a[13]);                                     \
    a[14] = fmaf(v, q2f<2>((d).w), a[14]);                                     \
    a[15] = fmaf(v, q2f<3>((d).w), a[15]);

// spmm v4: wave per row; 16 edge-slots (lane>>2) x 4 dim-lanes (lane&3).
// One dwordx4 gather = 16 lines in flight. Predicated tail body (clamped
// index, v masked 0; Zq is NaN-free since cvt_pk_fp8_f32 saturates).
template <int L3>
__global__ __launch_bounds__(256, 8) void spmm16_k(
    const int* __restrict__ rp, const unsigned* __restrict__ epk,
    const unsigned char* __restrict__ Zq, const float* __restrict__ bias,
    const float* __restrict__ xa, const float* __restrict__ xb,
    float* __restrict__ xout, int n) {
    int lane = threadIdx.x & 63;
    int dim4 = lane & 3, slot = lane >> 2;
    int row = (int)((blockIdx.x * blockDim.x + threadIdx.x) >> 6);
    if (row >= n) return;
    // final lane<->dim mapping after the dim-splitting reduce (bit-permuted)
    int dimL = dim4 * 16 + ((lane >> 2) & 1) * 8 + ((lane >> 3) & 1) * 4 +
               ((lane >> 4) & 1) * 2 + ((lane >> 5) & 1);
    float bv = bias[dimL];  // preload, hides under the gather chain
    const unsigned char* zb = Zq + (dim4 << 4);
    int s = rp[row], e = rp[row + 1];

    float a[16];
#pragma unroll
    for (int k = 0; k < 16; ++k) a[k] = 0.f;

    int j = s;
    for (; j + 32 <= e; j += 32) {  // 2 c-loads + 2 gathers, loads first
        unsigned c0 = __builtin_nontemporal_load(epk + j + slot);
        unsigned c1 = __builtin_nontemporal_load(epk + j + 16 + slot);
        u32x4 d0 = *(const u32x4*)(zb + ((c0 >> 8) << 6));
        u32x4 d1 = *(const u32x4*)(zb + ((c1 >> 8) << 6));
        float v0 = q2f<0>(c0);
        float v1 = q2f<0>(c1);
        FMA16(v0, d0)
        FMA16(v1, d1)
    }
    if (j < e) {  // predicated 32-edge body: whole remainder in one burst
        int i0 = min(j + slot, e - 1);
        int i1 = min(j + 16 + slot, e - 1);
        unsigned c0 = __builtin_nontemporal_load(epk + i0);
        unsigned c1 = __builtin_nontemporal_load(epk + i1);
        u32x4 d0 = *(const u32x4*)(zb + ((c0 >> 8) << 6));
        u32x4 d1 = *(const u32x4*)(zb + ((c1 >> 8) << 6));
        float v0 = (j + slot < e) ? q2f<0>(c0) : 0.f;
        float v1 = (j + 16 + slot < e) ? q2f<0>(c1) : 0.f;
        FMA16(v0, d0)
        FMA16(v1, d1)
    }

    // residual reads issue before the reduce; latency hides under shuffles
    float ra = 0.f, rb = 0.f;
    if (L3) {
        ra = __builtin_nontemporal_load(xa + (size_t)row * 64 + dimL);
        rb = __builtin_nontemporal_load(xb + (size_t)row * 64 + dimL);
    }

    // recursive-halving reduce over 16 slots with dim-splitting:
    // each round keep half the dims, donate the other half to the partner.
    float r8[8];
    {
        bool h = (lane & 4) != 0;
#pragma unroll
        for (int k = 0; k < 8; ++k) {
            float keep = h ? a[8 + k] : a[k];
            float give = h ? a[k] : a[8 + k];
            r8[k] = keep + __shfl_xor(give, 4, 64);
        }
    }
    float r4[4];
    {
        bool h = (lane & 8) != 0;
#pragma unroll
        for (int k = 0; k < 4; ++k) {
            float keep = h ? r8[4 + k] : r8[k];
            float give = h ? r8[k] : r8[4 + k];
            r4[k] = keep + __shfl_xor(give, 8, 64);
        }
    }
    float r2[2];
    {
        bool h = (lane & 16) != 0;
#pragma unroll
        for (int k = 0; k < 2; ++k) {
            float keep = h ? r4[2 + k] : r4[k];
            float give = h ? r4[k] : r4[2 + k];
            r2[k] = keep + __shfl_xor(give, 16, 64);
        }
    }
    float tot;
    {
        bool h = (lane & 32) != 0;
        float keep = h ? r2[1] : r2[0];
        float give = h ? r2[0] : r2[1];
        tot = keep + __shfl_xor(give, 32, 64);
    }

    float o = fmaxf(fmaf(tot, 0.0625f, bv), 0.f);
    if (L3) o += ra + rb;
    xout[(size_t)row * 64 + dimL] = o;  // all 64 lanes store (256B/row)
}

// Pool: batch sorted -> run-length accumulate 64 nodes per wave, one
// atomicAdd per segment boundary per lane. h already = x1+x2+x3.
__global__ void pool_k(const float* __restrict__ h, const int* __restrict__ batch,
                       float* __restrict__ sums, int* __restrict__ cnts, int n) {
    int lane = threadIdx.x & 63;
    int w = (blockIdx.x * blockDim.x + threadIdx.x) >> 6;
    int node0 = w * 64;
    if (node0 >= n) return;
    int cur = batch[node0];
    float acc = 0.f;
    int cnt = 0;
    int end = min(node0 + 64, n);
    for (int nd = node0; nd < end; ++nd) {
        int bg = batch[nd];  // wave-uniform
        if (bg != cur) {
            atomicAdd(&sums[(size_t)cur * 64 + lane], acc);
            if (lane == 0) atomicAdd(&cnts[cur], cnt);
            acc = 0.f;
            cnt = 0;
            cur = bg;
        }
        acc += h[(size_t)nd * 64 + lane];
        cnt++;
    }
    atomicAdd(&sums[(size_t)cur * 64 + lane], acc);
    if (lane == 0) atomicAdd(&cnts[cur], cnt);
}

// Head: pooled = sums/(3*cnt); out = softmax(pooled @ Wl + bl). Wave per graph.
__global__ void final_k(const float* __restrict__ sums, const int* __restrict__ cnts,
                        const float* __restrict__ Wl, const float* __restrict__ bl,
                        float* __restrict__ out, int G) {
    int lane = threadIdx.x & 63;
    int g = (blockIdx.x * blockDim.x + threadIdx.x) >> 6;
    if (g >= G) return;
    float c = (float)max(cnts[g], 1);
    float s = sums[(size_t)g * 64 + lane] / (3.f * c);
    float y = (lane < 10) ? bl[lane] : -1e30f;
    for (int k = 0; k < 64; ++k) {
        float sk = __shfl(s, k, 64);
        if (lane < 10) y = fmaf(sk, Wl[k * 10 + lane], y);
    }
    float m = y;
#pragma unroll
    for (int off = 8; off; off >>= 1) m = fmaxf(m, __shfl_xor(m, off, 16));
    float ey = (lane < 10) ? __expf(y - m) : 0.f;
    float sm = ey;
#pragma unroll
    for (int off = 8; off; off >>= 1) sm += __shfl_xor(sm, off, 16);
    if (lane < 10) out[(size_t)g * 10 + lane] = ey / sm;
}

extern "C" void kernel_launch(void* const* d_in, const int* in_sizes, int n_in,
                              void* d_out, int out_size, void* d_ws, size_t ws_size,
                              hipStream_t stream) {
    const float* x = (const float*)d_in[0];
    const int* rows = (const int*)d_in[1];
    const int* cols = (const int*)d_in[2];
    const float* vals = (const float*)d_in[3];
    const int* batch = (const int*)d_in[4];
    const float* W1 = (const float*)d_in[5];
    const float* b1 = (const float*)d_in[6];
    const float* W2 = (const float*)d_in[7];
    const float* b2 = (const float*)d_in[8];
    const float* W3 = (const float*)d_in[9];
    const float* b3 = (const float*)d_in[10];
    const float* Wl = (const float*)d_in[11];
    const float* bl = (const float*)d_in[12];
    float* out = (float*)d_out;

    const int N = in_sizes[4];   // n_nodes (<= 131072)
    const int E = in_sizes[1];   // n_edges
    const int G = out_size / 10; // n_graphs
    const int K = (N + BROWS - 1) >> BSHIFT;

    char* p = (char*)d_ws;
    size_t off = 0;
    auto alloc = [&](size_t bytes) -> void* {
        off = (off + 255) & ~(size_t)255;
        void* r = (void*)(p + off);
        off += bytes;
        return r;
    };
    size_t featF = (size_t)N * 64 * 4;
    int* bhist = (int*)alloc(MAXK * 4);
    int* bstart = (int*)alloc((MAXK + 1) * 4);
    int* bcur = (int*)alloc(MAXK * 16 * 4);
    int* rp = (int*)alloc((size_t)(N + 2) * 4);
    // pk (bucketed, pre-sort) is dead after sort_k; alias with h (written
    // only by the layer-3 spmm, far after sort_k).
    void* regP = alloc((size_t)E * 8 > featF ? (size_t)E * 8 : featF);
    unsigned* epk = (unsigned*)alloc((size_t)E * 4);  // packed sorted edges
    unsigned char* ZqA = (unsigned char*)alloc((size_t)N * 64);
    unsigned char* ZqB = (unsigned char*)alloc((size_t)N * 64);
    float* x1 = (float*)alloc(featF);
    float* x2 = (float*)alloc(featF);
    float* sums = (float*)alloc((size_t)G * 64 * 4);
    int* cnts = (int*)alloc((size_t)G * 4);

    unsigned long long* pk = (unsigned long long*)regP;
    float* h = (float*)regP;

    (void)hipMemsetAsync(bhist, 0, MAXK * 4, stream);

    int cb = (E + CHUNK - 1) / CHUNK;
    bhist_k<<<cb, 512, 0, stream>>>(rows, bhist, E);
    bscan_k<<<1, MAXK, 0, stream>>>(bhist, bstart, bcur, rp, sums, cnts, K, E, N, G);
    binpass_k<<<cb, 512, 0, stream>>>(rows, cols, vals, bcur, pk, E);
    sort_k<<<K, 512, 0, stream>>>(bstart, pk, rp, epk, N);

    int rb = (N + 3) / 4;  // wave-per-row blocks
    dense5_k<<<rb, 256, 0, stream>>>(x, W1, ZqA, N);
    spmm16_k<0><<<rb, 256, 0, stream>>>(rp, epk, ZqA, b1, nullptr, nullptr, x1, N);
    dense64_k<<<512, 256, 0, stream>>>(x1, W2, ZqB, N);
    spmm16_k<0><<<rb, 256, 0, stream>>>(rp, epk, ZqB, b2, nullptr, nullptr, x2, N);
    dense64_k<<<512, 256, 0, stream>>>(x2, W3, ZqA, N);
    spmm16_k<1><<<rb, 256, 0, stream>>>(rp, epk, ZqA, b3, x1, x2, h, N);

    int pw = (N + 63) / 64;
    pool_k<<<(pw + 3) / 4, 256, 0, stream>>>(h, batch, sums, cnts, N);
    final_k<<<(G + 3) / 4, 256, 0, stream>>>(sums, cnts, Wl, bl, out, G);
}

// Round 6
// 378.118 us; speedup vs baseline: 1.7210x; 1.0367x over previous
//
#include <hip/hip_runtime.h>

// GCN3: 3x (COO spmm -> Linear(64) -> ReLU), segment-mean pool, softmax head.
// relu(spmm(X)@W + b) == relu(spmm(X@W) + b): dense transform first, then
// PULL-spmm from fp8 Z (e4m3, 64B/row). Edge record 4B: (col<<14)|fp8(val*16)
// (col pre-scaled so gather byte-offset is just rec>>8).
// spmm v6: wave = 16 edge-slots x 4 dim-lanes, dwordx4 gathers (16 lines in
// flight per instr); PACKED core: v_cvt_pk_f32_fp8 (2 fp8->f32/op) +
// f32x2 accumulators (v_pk_fma_f32) halve the VALU stream vs scalar
// cvt+fma (v5 was 62% VALUBusy -> VALU-bound). Predicated 32-edge tail.
// 16 acc/lane reduced by recursive halving with dim-splitting.
// dense64 v5: MFMA 16x16x32 bf16, W fragments cvt_pk'd once per wave.
// CSR build: LDS-staged binpass into 512-row buckets, per-bucket counting sort.

#define BSHIFT 9
#define BROWS  (1 << BSHIFT)   // 512 rows per bucket
#define MAXK   256             // supports N <= 131072
#define CHUNK  6144            // edges per binpass/bhist block

typedef float f32x2 __attribute__((ext_vector_type(2)));
typedef float f32x4 __attribute__((ext_vector_type(4)));
typedef unsigned u32x4 __attribute__((ext_vector_type(4)));
typedef short bf16x8 __attribute__((ext_vector_type(8)));

__device__ inline unsigned char f2q(float f) {  // fp8 e4m3 RNE (saturating)
    unsigned p = __builtin_amdgcn_cvt_pk_fp8_f32(f, f, 0u, false);
    return (unsigned char)(p & 0xffu);
}
template <int SEL>
__device__ inline float q2f(unsigned q) {  // byte-select fp8->f32 (SEL = ICE)
    return __builtin_amdgcn_cvt_f32_fp8(q, SEL);
}
template <int HI>  // 2 fp8 (bytes 2*HI, 2*HI+1) -> 2 f32, one instr
__device__ inline f32x2 q2f2(unsigned q) {
#if __has_builtin(__builtin_amdgcn_cvt_pk_f32_fp8)
    return __builtin_amdgcn_cvt_pk_f32_fp8(q, HI != 0);
#else
    f32x2 r;
    r.x = q2f<2 * HI>(q);
    r.y = q2f<2 * HI + 1>(q);
    return r;
#endif
}

// pack 8 f32 (k ascending: lo.x..lo.w, hi.x..hi.w) -> bf16x8, RNE
__device__ inline bf16x8 pack_bf8(f32x4 lo, f32x4 hi) {
    union { u32x4 u; bf16x8 h; } r;
    asm("v_cvt_pk_bf16_f32 %0, %1, %2" : "=v"(r.u.x) : "v"(lo.x), "v"(lo.y));
    asm("v_cvt_pk_bf16_f32 %0, %1, %2" : "=v"(r.u.y) : "v"(lo.z), "v"(lo.w));
    asm("v_cvt_pk_bf16_f32 %0, %1, %2" : "=v"(r.u.z) : "v"(hi.x), "v"(hi.y));
    asm("v_cvt_pk_bf16_f32 %0, %1, %2" : "=v"(r.u.w) : "v"(hi.z), "v"(hi.w));
    return r.h;
}

// Per-block LDS histogram of bucket ids -> global bucket counts.
__global__ __launch_bounds__(512) void bhist_k(const int* __restrict__ rows,
                                               int* __restrict__ bhist, int E) {
    __shared__ int h[MAXK];
    int tx = threadIdx.x;
    if (tx < MAXK) h[tx] = 0;
    __syncthreads();
    int e0 = blockIdx.x * CHUNK, ee = min(e0 + CHUNK, E);
    for (int e = e0 + tx; e < ee; e += 512)
        atomicAdd(&h[rows[e] >> BSHIFT], 1);
    __syncthreads();
    if (tx < MAXK && h[tx]) atomicAdd(&bhist[tx], h[tx]);
}

// Exclusive scan of bucket counts (single block); init padded cursors; rp[N]=E.
// Also zeroes the pool buffers (sums/cnts) so those memset dispatches go away.
__global__ __launch_bounds__(MAXK) void bscan_k(const int* __restrict__ bhist,
                                                int* __restrict__ bstart,
                                                int* __restrict__ bcur,
                                                int* __restrict__ rp,
                                                float* __restrict__ sums,
                                                int* __restrict__ cnts,
                                                int K, int E, int N, int G) {
    __shared__ int s[MAXK];
    int tx = threadIdx.x;
    f32x4* s4 = (f32x4*)sums;
    for (int i = tx; i < G * 16; i += MAXK) s4[i] = 0;
    for (int i = tx; i < G; i += MAXK) cnts[i] = 0;
    int v = (tx < K) ? bhist[tx] : 0;
    s[tx] = v;
    __syncthreads();
    for (int off = 1; off < MAXK; off <<= 1) {
        int t = (tx >= off) ? s[tx - off] : 0;
        __syncthreads();
        s[tx] += t;
        __syncthreads();
    }
    if (tx < K) {
        bstart[tx] = s[tx] - v;
        bcur[tx * 16] = s[tx] - v;  // 1 cursor per 64B line
    }
    if (tx == K - 1) bstart[K] = E;
    if (tx == 0) rp[N] = E;
}

// Bin edges by 512-row bucket, staged in LDS so global writes are ~31-edge
// single-CU bursts. Record (u64): lo32=(col<<9)|(row&511), hi32=val bits.
__global__ __launch_bounds__(512) void binpass_k(
    const int* __restrict__ rows, const int* __restrict__ cols,
    const float* __restrict__ vals, int* __restrict__ bcur,
    unsigned long long* __restrict__ pk, int E) {
    __shared__ int h[MAXK], base[MAXK], gbase[MAXK], lcnt[MAXK];
    __shared__ unsigned long long st[CHUNK];  // 48 KB
    int tx = threadIdx.x;
    if (tx < MAXK) h[tx] = 0;
    __syncthreads();
    int e0 = blockIdx.x * CHUNK, ee = min(e0 + CHUNK, E);
    for (int e = e0 + tx; e < ee; e += 512)
        atomicAdd(&h[rows[e] >> BSHIFT], 1);
    __syncthreads();
    int v = (tx < MAXK) ? h[tx] : 0;
    if (tx < MAXK) lcnt[tx] = v;  // scan buffer
    __syncthreads();
    for (int off = 1; off < MAXK; off <<= 1) {
        int t = (tx >= off && tx < MAXK) ? lcnt[tx - off] : 0;
        __syncthreads();
        if (tx < MAXK) lcnt[tx] += t;
        __syncthreads();
    }
    if (tx < MAXK) {
        base[tx] = lcnt[tx] - v;
        if (v) gbase[tx] = atomicAdd(&bcur[tx * 16], v);
        lcnt[tx] = 0;
    }
    __syncthreads();
    for (int e = e0 + tx; e < ee; e += 512) {
        int r = rows[e];
        int c = cols[e];
        float vv = vals[e];
        int b = r >> BSHIFT;
        int p = base[b] + atomicAdd(&lcnt[b], 1);
        unsigned lo = ((unsigned)c << BSHIFT) | (unsigned)(r & (BROWS - 1));
        st[p] = (unsigned long long)lo
              | ((unsigned long long)(unsigned)__float_as_int(vv) << 32);
    }
    __syncthreads();
    // flush contiguous per-bucket runs, wave-parallel. NT safe: 64 lanes x 8B
    // = 512B contiguous per instruction (full lines covered).
    int lane = tx & 63, wid = tx >> 6;
    for (int b = wid; b < MAXK; b += 8) {
        int cnt = h[b];
        if (!cnt) continue;
        int lb = base[b], gb = gbase[b];
        for (int i = lane; i < cnt; i += 64)
            __builtin_nontemporal_store(st[lb + i], &pk[gb + i]);
    }
}

// Per-bucket counting sort: one block per bucket. LDS hist over 512 rows,
// scan -> rp, then local scatter into the bucket's contiguous epk window.
// CACHED loads/stores (sub-line scatter: L2 must assemble the lines).
// Output record (4B): (col << 14) | fp8(val * 16)  [col<<14 = byteoff<<8].
__global__ __launch_bounds__(512) void sort_k(
    const int* __restrict__ bstart, const unsigned long long* __restrict__ pk,
    int* __restrict__ rp, unsigned* __restrict__ epk, int n) {
    __shared__ int hist[BROWS], cur[BROWS];
    int tx = threadIdx.x;
    int b = blockIdx.x;
    int row0 = b << BSHIFT;
    int s = bstart[b], e = bstart[b + 1];
    hist[tx] = 0;
    __syncthreads();
    for (int j = s + tx; j < e; j += 512) {
        unsigned lo = (unsigned)pk[j];
        atomicAdd(&hist[lo & (BROWS - 1)], 1);
    }
    __syncthreads();
    int v = hist[tx];
    for (int off = 1; off < BROWS; off <<= 1) {
        int t = (tx >= off) ? hist[tx - off] : 0;
        __syncthreads();
        hist[tx] += t;
        __syncthreads();
    }
    int excl = hist[tx] - v;
    cur[tx] = excl;
    if (row0 + tx < n) rp[row0 + tx] = s + excl;
    __syncthreads();
    for (int j = s + tx; j < e; j += 512) {
        unsigned long long rec = pk[j];
        unsigned lo = (unsigned)rec;
        float vv = __int_as_float((int)(unsigned)(rec >> 32));
        int r = (int)(lo & (BROWS - 1));
        int q = atomicAdd(&cur[r], 1);
        epk[s + q] = ((lo >> BSHIFT) << 14) | (unsigned)f2q(vv * 16.f);
    }
}

// Zq = fp8(X @ W1), X:[n,5]. Wave per row, lane = out dim.
__global__ __launch_bounds__(256) void dense5_k(
    const float* __restrict__ X, const float* __restrict__ W,
    unsigned char* __restrict__ Zq, int n) {
    int lane = threadIdx.x & 63;
    int row = (blockIdx.x * blockDim.x + threadIdx.x) >> 6;
    if (row >= n) return;
    float w0 = W[lane], w1 = W[64 + lane], w2 = W[128 + lane],
          w3 = W[192 + lane], w4 = W[256 + lane];
    float xv = (lane < 5) ? X[(size_t)row * 5 + lane] : 0.f;
    float y = __shfl(xv, 0, 64) * w0;
    y = fmaf(__shfl(xv, 1, 64), w1, y);
    y = fmaf(__shfl(xv, 2, 64), w2, y);
    y = fmaf(__shfl(xv, 3, 64), w3, y);
    y = fmaf(__shfl(xv, 4, 64), w4, y);
    Zq[(size_t)row * 64 + lane] = f2q(y);
}

// dense64 v5: Zq = fp8(X @ W) via mfma_f32_16x16x32_bf16. Wave = 16-row
// tile x 64 cols. B (W) fragments built once per wave: frag (c,m) holds
// B[k=32m+8*(l>>4)+i][col=16c+(l&15)]. Per tile: A frags from 4 f32x4 loads
// (lane: row=l&15, k=8*(l>>4)+i (+32m)), 8 MFMAs (K-accumulate), D written
// as fp8 bytes: row=rowb+4*(l>>4)+j, col=16c+(l&15).
__global__ __launch_bounds__(256, 4) void dense64_k(
    const float* __restrict__ X, const float* __restrict__ W,
    unsigned char* __restrict__ Zq, int n) {
    int lane = threadIdx.x & 63, wid = threadIdx.x >> 6;
    int l15 = lane & 15, lk = lane >> 4;
    bf16x8 bw[4][2];
#pragma unroll
    for (int c = 0; c < 4; ++c) {
#pragma unroll
        for (int m = 0; m < 2; ++m) {
            const float* wp = W + (size_t)(32 * m + 8 * lk) * 64 + 16 * c + l15;
            f32x4 lo, hi;
            lo.x = wp[0];   lo.y = wp[64];  lo.z = wp[128]; lo.w = wp[192];
            hi.x = wp[256]; hi.y = wp[320]; hi.z = wp[384]; hi.w = wp[448];
            bw[c][m] = pack_bf8(lo, hi);
        }
    }
    int nt = (n + 15) >> 4;
    int nwv = (int)(gridDim.x * 4);
    for (int t = blockIdx.x * 4 + wid; t < nt; t += nwv) {
        int rowb = t << 4;
        int ar = min(rowb + l15, n - 1);  // clamped A row (stores guarded)
        const float* xr = X + (size_t)ar * 64 + 8 * lk;
        f32x4 a0 = *(const f32x4*)(xr);
        f32x4 a1 = *(const f32x4*)(xr + 4);
        f32x4 a2 = *(const f32x4*)(xr + 32);
        f32x4 a3 = *(const f32x4*)(xr + 36);
        bf16x8 A0 = pack_bf8(a0, a1);
        bf16x8 A1 = pack_bf8(a2, a3);
        f32x4 acc0 = 0, acc1 = 0, acc2 = 0, acc3 = 0;
        acc0 = __builtin_amdgcn_mfma_f32_16x16x32_bf16(A0, bw[0][0], acc0, 0, 0, 0);
        acc1 = __builtin_amdgcn_mfma_f32_16x16x32_bf16(A0, bw[1][0], acc1, 0, 0, 0);
        acc2 = __builtin_amdgcn_mfma_f32_16x16x32_bf16(A0, bw[2][0], acc2, 0, 0, 0);
        acc3 = __builtin_amdgcn_mfma_f32_16x16x32_bf16(A0, bw[3][0], acc3, 0, 0, 0);
        acc0 = __builtin_amdgcn_mfma_f32_16x16x32_bf16(A1, bw[0][1], acc0, 0, 0, 0);
        acc1 = __builtin_amdgcn_mfma_f32_16x16x32_bf16(A1, bw[1][1], acc1, 0, 0, 0);
        acc2 = __builtin_amdgcn_mfma_f32_16x16x32_bf16(A1, bw[2][1], acc2, 0, 0, 0);
        acc3 = __builtin_amdgcn_mfma_f32_16x16x32_bf16(A1, bw[3][1], acc3, 0, 0, 0);
#pragma unroll
        for (int j = 0; j < 4; ++j) {
            int r = rowb + 4 * lk + j;
            if (r < n) {
                unsigned char* zp = Zq + (size_t)r * 64 + l15;
                zp[0]  = f2q(acc0[j]);
                zp[16] = f2q(acc1[j]);
                zp[32] = f2q(acc2[j]);
                zp[48] = f2q(acc3[j]);
            }
        }
    }
}

// Packed core: one edge's 16B Zq chunk into a2[0..7] (f32x2 = 2 dims each).
// 8 cvt_pk + 8 pk_fma per edge (v5 scalar: 16 cvt + 16 fma).
#define FMA16P(vv2, d)                                                         \
    a2[0] += (vv2) * q2f2<0>((d).x);                                           \
    a2[1] += (vv2) * q2f2<1>((d).x);                                           \
    a2[2] += (vv2) * q2f2<0>((d).y);                                           \
    a2[3] += (vv2) * q2f2<1>((d).y);                                           \
    a2[4] += (vv2) * q2f2<0>((d).z);                                           \
    a2[5] += (vv2) * q2f2<1>((d).z);                                           \
    a2[6] += (vv2) * q2f2<0>((d).w);                                           \
    a2[7] += (vv2) * q2f2<1>((d).w);

// spmm v6: wave per row; 16 edge-slots (lane>>2) x 4 dim-lanes (lane&3).
// One dwordx4 gather = 16 lines in flight. Predicated tail body (clamped
// index, v masked 0; Zq is NaN-free since cvt_pk_fp8_f32 saturates).
template <int L3>
__global__ __launch_bounds__(256, 8) void spmm16_k(
    const int* __restrict__ rp, const unsigned* __restrict__ epk,
    const unsigned char* __restrict__ Zq, const float* __restrict__ bias,
    const float* __restrict__ xa, const float* __restrict__ xb,
    float* __restrict__ xout, int n) {
    int lane = threadIdx.x & 63;
    int dim4 = lane & 3, slot = lane >> 2;
    int row = (int)((blockIdx.x * blockDim.x + threadIdx.x) >> 6);
    if (row >= n) return;
    // final lane<->dim mapping after the dim-splitting reduce (bit-permuted)
    int dimL = dim4 * 16 + ((lane >> 2) & 1) * 8 + ((lane >> 3) & 1) * 4 +
               ((lane >> 4) & 1) * 2 + ((lane >> 5) & 1);
    float bv = bias[dimL];  // preload, hides under the gather chain
    const unsigned char* zb = Zq + (dim4 << 4);
    int s = rp[row], e = rp[row + 1];

    f32x2 a2[8];
#pragma unroll
    for (int k = 0; k < 8; ++k) a2[k] = 0;

    int j = s;
    for (; j + 32 <= e; j += 32) {  // 2 c-loads + 2 gathers, loads first
        unsigned c0 = __builtin_nontemporal_load(epk + j + slot);
        unsigned c1 = __builtin_nontemporal_load(epk + j + 16 + slot);
        u32x4 d0 = *(const u32x4*)(zb + (c0 >> 8));  // c>>8 = col*64
        u32x4 d1 = *(const u32x4*)(zb + (c1 >> 8));
        float v0 = q2f<0>(c0);
        float v1 = q2f<0>(c1);
        f32x2 vv0 = {v0, v0}, vv1 = {v1, v1};
        FMA16P(vv0, d0)
        FMA16P(vv1, d1)
    }
    if (j < e) {  // predicated 32-edge body: whole remainder in one burst
        int i0 = min(j + slot, e - 1);
        int i1 = min(j + 16 + slot, e - 1);
        unsigned c0 = __builtin_nontemporal_load(epk + i0);
        unsigned c1 = __builtin_nontemporal_load(epk + i1);
        u32x4 d0 = *(const u32x4*)(zb + (c0 >> 8));
        u32x4 d1 = *(const u32x4*)(zb + (c1 >> 8));
        float v0 = (j + slot < e) ? q2f<0>(c0) : 0.f;
        float v1 = (j + 16 + slot < e) ? q2f<0>(c1) : 0.f;
        f32x2 vv0 = {v0, v0}, vv1 = {v1, v1};
        FMA16P(vv0, d0)
        FMA16P(vv1, d1)
    }

    // residual reads issue before the reduce; latency hides under shuffles
    float ra = 0.f, rb = 0.f;
    if (L3) {
        ra = __builtin_nontemporal_load(xa + (size_t)row * 64 + dimL);
        rb = __builtin_nontemporal_load(xb + (size_t)row * 64 + dimL);
    }

    // re-extract scalars (constant indices -> stays in registers)
    float a[16];
#pragma unroll
    for (int k = 0; k < 16; ++k) a[k] = a2[k >> 1][k & 1];

    // recursive-halving reduce over 16 slots with dim-splitting:
    // each round keep half the dims, donate the other half to the partner.
    float r8[8];
    {
        bool h = (lane & 4) != 0;
#pragma unroll
        for (int k = 0; k < 8; ++k) {
            float keep = h ? a[8 + k] : a[k];
            float give = h ? a[k] : a[8 + k];
            r8[k] = keep + __shfl_xor(give, 4, 64);
        }
    }
    float r4[4];
    {
        bool h = (lane & 8) != 0;
#pragma unroll
        for (int k = 0; k < 4; ++k) {
            float keep = h ? r8[4 + k] : r8[k];
            float give = h ? r8[k] : r8[4 + k];
            r4[k] = keep + __shfl_xor(give, 8, 64);
        }
    }
    float r2[2];
    {
        bool h = (lane & 16) != 0;
#pragma unroll
        for (int k = 0; k < 2; ++k) {
            float keep = h ? r4[2 + k] : r4[k];
            float give = h ? r4[k] : r4[2 + k];
            r2[k] = keep + __shfl_xor(give, 16, 64);
        }
    }
    float tot;
    {
        bool h = (lane & 32) != 0;
        float keep = h ? r2[1] : r2[0];
        float give = h ? r2[0] : r2[1];
        tot = keep + __shfl_xor(give, 32, 64);
    }

    float o = fmaxf(fmaf(tot, 0.0625f, bv), 0.f);
    if (L3) o += ra + rb;
    xout[(size_t)row * 64 + dimL] = o;  // all 64 lanes store (256B/row)
}

// Pool: batch sorted -> run-length accumulate NODE_CHUNK nodes per wave, one
// atomicAdd per segment boundary per lane. h already = x1+x2+x3.
// Chunk 16 (was 64): 4x waves, 1/4 serial chain; extra boundary atomics noise.
#define NODE_CHUNK 16
__global__ void pool_k(const float* __restrict__ h, const int* __restrict__ batch,
                       float* __restrict__ sums, int* __restrict__ cnts, int n) {
    int lane = threadIdx.x & 63;
    int w = (blockIdx.x * blockDim.x + threadIdx.x) >> 6;
    int node0 = w * NODE_CHUNK;
    if (node0 >= n) return;
    int cur = batch[node0];
    float acc = 0.f;
    int cnt = 0;
    int end = min(node0 + NODE_CHUNK, n);
    for (int nd = node0; nd < end; ++nd) {
        int bg = batch[nd];  // wave-uniform
        if (bg != cur) {
            atomicAdd(&sums[(size_t)cur * 64 + lane], acc);
            if (lane == 0) atomicAdd(&cnts[cur], cnt);
            acc = 0.f;
            cnt = 0;
            cur = bg;
        }
        acc += h[(size_t)nd * 64 + lane];
        cnt++;
    }
    atomicAdd(&sums[(size_t)cur * 64 + lane], acc);
    if (lane == 0) atomicAdd(&cnts[cur], cnt);
}

// Head: pooled = sums/(3*cnt); out = softmax(pooled @ Wl + bl). Wave per graph.
__global__ void final_k(const float* __restrict__ sums, const int* __restrict__ cnts,
                        const float* __restrict__ Wl, const float* __restrict__ bl,
                        float* __restrict__ out, int G) {
    int lane = threadIdx.x & 63;
    int g = (blockIdx.x * blockDim.x + threadIdx.x) >> 6;
    if (g >= G) return;
    float c = (float)max(cnts[g], 1);
    float s = sums[(size_t)g * 64 + lane] / (3.f * c);
    float y = (lane < 10) ? bl[lane] : -1e30f;
    for (int k = 0; k < 64; ++k) {
        float sk = __shfl(s, k, 64);
        if (lane < 10) y = fmaf(sk, Wl[k * 10 + lane], y);
    }
    float m = y;
#pragma unroll
    for (int off = 8; off; off >>= 1) m = fmaxf(m, __shfl_xor(m, off, 16));
    float ey = (lane < 10) ? __expf(y - m) : 0.f;
    float sm = ey;
#pragma unroll
    for (int off = 8; off; off >>= 1) sm += __shfl_xor(sm, off, 16);
    if (lane < 10) out[(size_t)g * 10 + lane] = ey / sm;
}

extern "C" void kernel_launch(void* const* d_in, const int* in_sizes, int n_in,
                              void* d_out, int out_size, void* d_ws, size_t ws_size,
                              hipStream_t stream) {
    const float* x = (const float*)d_in[0];
    const int* rows = (const int*)d_in[1];
    const int* cols = (const int*)d_in[2];
    const float* vals = (const float*)d_in[3];
    const int* batch = (const int*)d_in[4];
    const float* W1 = (const float*)d_in[5];
    const float* b1 = (const float*)d_in[6];
    const float* W2 = (const float*)d_in[7];
    const float* b2 = (const float*)d_in[8];
    const float* W3 = (const float*)d_in[9];
    const float* b3 = (const float*)d_in[10];
    const float* Wl = (const float*)d_in[11];
    const float* bl = (const float*)d_in[12];
    float* out = (float*)d_out;

    const int N = in_sizes[4];   // n_nodes (<= 131072)
    const int E = in_sizes[1];   // n_edges
    const int G = out_size / 10; // n_graphs
    const int K = (N + BROWS - 1) >> BSHIFT;

    char* p = (char*)d_ws;
    size_t off = 0;
    auto alloc = [&](size_t bytes) -> void* {
        off = (off + 255) & ~(size_t)255;
        void* r = (void*)(p + off);
        off += bytes;
        return r;
    };
    size_t featF = (size_t)N * 64 * 4;
    int* bhist = (int*)alloc(MAXK * 4);
    int* bstart = (int*)alloc((MAXK + 1) * 4);
    int* bcur = (int*)alloc(MAXK * 16 * 4);
    int* rp = (int*)alloc((size_t)(N + 2) * 4);
    // pk (bucketed, pre-sort) is dead after sort_k; alias with h (written
    // only by the layer-3 spmm, far after sort_k).
    void* regP = alloc((size_t)E * 8 > featF ? (size_t)E * 8 : featF);
    unsigned* epk = (unsigned*)alloc((size_t)E * 4);  // packed sorted edges
    unsigned char* ZqA = (unsigned char*)alloc((size_t)N * 64);
    unsigned char* ZqB = (unsigned char*)alloc((size_t)N * 64);
    float* x1 = (float*)alloc(featF);
    float* x2 = (float*)alloc(featF);
    float* sums = (float*)alloc((size_t)G * 64 * 4);
    int* cnts = (int*)alloc((size_t)G * 4);

    unsigned long long* pk = (unsigned long long*)regP;
    float* h = (float*)regP;

    (void)hipMemsetAsync(bhist, 0, MAXK * 4, stream);

    int cb = (E + CHUNK - 1) / CHUNK;
    bhist_k<<<cb, 512, 0, stream>>>(rows, bhist, E);
    bscan_k<<<1, MAXK, 0, stream>>>(bhist, bstart, bcur, rp, sums, cnts, K, E, N, G);
    binpass_k<<<cb, 512, 0, stream>>>(rows, cols, vals, bcur, pk, E);
    sort_k<<<K, 512, 0, stream>>>(bstart, pk, rp, epk, N);

    int rb = (N + 3) / 4;  // wave-per-row blocks
    dense5_k<<<rb, 256, 0, stream>>>(x, W1, ZqA, N);
    spmm16_k<0><<<rb, 256, 0, stream>>>(rp, epk, ZqA, b1, nullptr, nullptr, x1, N);
    dense64_k<<<512, 256, 0, stream>>>(x1, W2, ZqB, N);
    spmm16_k<0><<<rb, 256, 0, stream>>>(rp, epk, ZqB, b2, nullptr, nullptr, x2, N);
    dense64_k<<<512, 256, 0, stream>>>(x2, W3, ZqA, N);
    spmm16_k<1><<<rb, 256, 0, stream>>>(rp, epk, ZqA, b3, x1, x2, h, N);

    int pw = (N + NODE_CHUNK - 1) / NODE_CHUNK;
    pool_k<<<(pw + 3) / 4, 256, 0, stream>>>(h, batch, sums, cnts, N);
    final_k<<<(G + 3) / 4, 256, 0, stream>>>(sums, cnts, Wl, bl, out, G);
}

// Round 7
// 372.303 us; speedup vs baseline: 1.7479x; 1.0156x over previous
//
#include <hip/hip_runtime.h>

// GCN3: 3x (COO spmm -> Linear(64) -> ReLU), segment-mean pool, softmax head.
// relu(spmm(X)@W + b) == relu(spmm(X@W) + b): dense transform first, then
// PULL-spmm from fp8 Z (e4m3, 64B/row). Edge record 4B: (col<<14)|fp8(val*16)
// (col pre-scaled so gather byte-offset is just rec>>8).
// spmm v7: wave = 16 edge-slots x 4 dim-lanes, dwordx4 gathers (16 lines in
// flight per instr); packed cvt_pk_f32_fp8 + f32x2 acc (v_pk_fma_f32).
// Scalar row (readfirstlane) -> rp via s_load; epilogue-only setup moved
// after the gather loop so the rp->c->gather chain issues first.
// v6 evidence: VALU packing gave only -2us (57% VALUBusy, 36% HBM, 63% occ)
// -> latency-structural; wave-per-row chain is ~2 serial memory hops.
// dense64 v7: MFMA 16x16x32 bf16 with W staged in LDS per block (v5/v6 built
// fragments from 64 stride-256B scalar loads = 16 lines/instr, every wave).
// LDS stride 65 pads lk=0..3 onto distinct banks (conflict-free ds_read).
// CSR build: LDS-staged binpass into 512-row buckets, per-bucket counting sort.

#define BSHIFT 9
#define BROWS  (1 << BSHIFT)   // 512 rows per bucket
#define MAXK   256             // supports N <= 131072
#define CHUNK  6144            // edges per binpass/bhist block

typedef float f32x2 __attribute__((ext_vector_type(2)));
typedef float f32x4 __attribute__((ext_vector_type(4)));
typedef unsigned u32x4 __attribute__((ext_vector_type(4)));
typedef short bf16x8 __attribute__((ext_vector_type(8)));

__device__ inline unsigned char f2q(float f) {  // fp8 e4m3 RNE (saturating)
    unsigned p = __builtin_amdgcn_cvt_pk_fp8_f32(f, f, 0u, false);
    return (unsigned char)(p & 0xffu);
}
template <int SEL>
__device__ inline float q2f(unsigned q) {  // byte-select fp8->f32 (SEL = ICE)
    return __builtin_amdgcn_cvt_f32_fp8(q, SEL);
}
template <int HI>  // 2 fp8 (bytes 2*HI, 2*HI+1) -> 2 f32, one instr
__device__ inline f32x2 q2f2(unsigned q) {
#if __has_builtin(__builtin_amdgcn_cvt_pk_f32_fp8)
    return __builtin_amdgcn_cvt_pk_f32_fp8(q, HI != 0);
#else
    f32x2 r;
    r.x = q2f<2 * HI>(q);
    r.y = q2f<2 * HI + 1>(q);
    return r;
#endif
}

// pack 8 f32 (k ascending: lo.x..lo.w, hi.x..hi.w) -> bf16x8, RNE
__device__ inline bf16x8 pack_bf8(f32x4 lo, f32x4 hi) {
    union { u32x4 u; bf16x8 h; } r;
    asm("v_cvt_pk_bf16_f32 %0, %1, %2" : "=v"(r.u.x) : "v"(lo.x), "v"(lo.y));
    asm("v_cvt_pk_bf16_f32 %0, %1, %2" : "=v"(r.u.y) : "v"(lo.z), "v"(lo.w));
    asm("v_cvt_pk_bf16_f32 %0, %1, %2" : "=v"(r.u.z) : "v"(hi.x), "v"(hi.y));
    asm("v_cvt_pk_bf16_f32 %0, %1, %2" : "=v"(r.u.w) : "v"(hi.z), "v"(hi.w));
    return r.h;
}

// Per-block LDS histogram of bucket ids -> global bucket counts.
__global__ __launch_bounds__(512) void bhist_k(const int* __restrict__ rows,
                                               int* __restrict__ bhist, int E) {
    __shared__ int h[MAXK];
    int tx = threadIdx.x;
    if (tx < MAXK) h[tx] = 0;
    __syncthreads();
    int e0 = blockIdx.x * CHUNK, ee = min(e0 + CHUNK, E);
    for (int e = e0 + tx; e < ee; e += 512)
        atomicAdd(&h[rows[e] >> BSHIFT], 1);
    __syncthreads();
    if (tx < MAXK && h[tx]) atomicAdd(&bhist[tx], h[tx]);
}

// Exclusive scan of bucket counts (single block); init padded cursors; rp[N]=E.
// Also zeroes the pool buffers (sums/cnts) so those memset dispatches go away.
__global__ __launch_bounds__(MAXK) void bscan_k(const int* __restrict__ bhist,
                                                int* __restrict__ bstart,
                                                int* __restrict__ bcur,
                                                int* __restrict__ rp,
                                                float* __restrict__ sums,
                                                int* __restrict__ cnts,
                                                int K, int E, int N, int G) {
    __shared__ int s[MAXK];
    int tx = threadIdx.x;
    f32x4* s4 = (f32x4*)sums;
    for (int i = tx; i < G * 16; i += MAXK) s4[i] = 0;
    for (int i = tx; i < G; i += MAXK) cnts[i] = 0;
    int v = (tx < K) ? bhist[tx] : 0;
    s[tx] = v;
    __syncthreads();
    for (int off = 1; off < MAXK; off <<= 1) {
        int t = (tx >= off) ? s[tx - off] : 0;
        __syncthreads();
        s[tx] += t;
        __syncthreads();
    }
    if (tx < K) {
        bstart[tx] = s[tx] - v;
        bcur[tx * 16] = s[tx] - v;  // 1 cursor per 64B line
    }
    if (tx == K - 1) bstart[K] = E;
    if (tx == 0) rp[N] = E;
}

// Bin edges by 512-row bucket, staged in LDS so global writes are ~31-edge
// single-CU bursts. Record (u64): lo32=(col<<9)|(row&511), hi32=val bits.
__global__ __launch_bounds__(512) void binpass_k(
    const int* __restrict__ rows, const int* __restrict__ cols,
    const float* __restrict__ vals, int* __restrict__ bcur,
    unsigned long long* __restrict__ pk, int E) {
    __shared__ int h[MAXK], base[MAXK], gbase[MAXK], lcnt[MAXK];
    __shared__ unsigned long long st[CHUNK];  // 48 KB
    int tx = threadIdx.x;
    if (tx < MAXK) h[tx] = 0;
    __syncthreads();
    int e0 = blockIdx.x * CHUNK, ee = min(e0 + CHUNK, E);
    for (int e = e0 + tx; e < ee; e += 512)
        atomicAdd(&h[rows[e] >> BSHIFT], 1);
    __syncthreads();
    int v = (tx < MAXK) ? h[tx] : 0;
    if (tx < MAXK) lcnt[tx] = v;  // scan buffer
    __syncthreads();
    for (int off = 1; off < MAXK; off <<= 1) {
        int t = (tx >= off && tx < MAXK) ? lcnt[tx - off] : 0;
        __syncthreads();
        if (tx < MAXK) lcnt[tx] += t;
        __syncthreads();
    }
    if (tx < MAXK) {
        base[tx] = lcnt[tx] - v;
        if (v) gbase[tx] = atomicAdd(&bcur[tx * 16], v);
        lcnt[tx] = 0;
    }
    __syncthreads();
    for (int e = e0 + tx; e < ee; e += 512) {
        int r = rows[e];
        int c = cols[e];
        float vv = vals[e];
        int b = r >> BSHIFT;
        int p = base[b] + atomicAdd(&lcnt[b], 1);
        unsigned lo = ((unsigned)c << BSHIFT) | (unsigned)(r & (BROWS - 1));
        st[p] = (unsigned long long)lo
              | ((unsigned long long)(unsigned)__float_as_int(vv) << 32);
    }
    __syncthreads();
    // flush contiguous per-bucket runs, wave-parallel. NT safe: 64 lanes x 8B
    // = 512B contiguous per instruction (full lines covered).
    int lane = tx & 63, wid = tx >> 6;
    for (int b = wid; b < MAXK; b += 8) {
        int cnt = h[b];
        if (!cnt) continue;
        int lb = base[b], gb = gbase[b];
        for (int i = lane; i < cnt; i += 64)
            __builtin_nontemporal_store(st[lb + i], &pk[gb + i]);
    }
}

// Per-bucket counting sort: one block per bucket. LDS hist over 512 rows,
// scan -> rp, then local scatter into the bucket's contiguous epk window.
// CACHED loads/stores (sub-line scatter: L2 must assemble the lines).
// Output record (4B): (col << 14) | fp8(val * 16)  [col<<14 = byteoff<<8].
__global__ __launch_bounds__(512) void sort_k(
    const int* __restrict__ bstart, const unsigned long long* __restrict__ pk,
    int* __restrict__ rp, unsigned* __restrict__ epk, int n) {
    __shared__ int hist[BROWS], cur[BROWS];
    int tx = threadIdx.x;
    int b = blockIdx.x;
    int row0 = b << BSHIFT;
    int s = bstart[b], e = bstart[b + 1];
    hist[tx] = 0;
    __syncthreads();
    for (int j = s + tx; j < e; j += 512) {
        unsigned lo = (unsigned)pk[j];
        atomicAdd(&hist[lo & (BROWS - 1)], 1);
    }
    __syncthreads();
    int v = hist[tx];
    for (int off = 1; off < BROWS; off <<= 1) {
        int t = (tx >= off) ? hist[tx - off] : 0;
        __syncthreads();
        hist[tx] += t;
        __syncthreads();
    }
    int excl = hist[tx] - v;
    cur[tx] = excl;
    if (row0 + tx < n) rp[row0 + tx] = s + excl;
    __syncthreads();
    for (int j = s + tx; j < e; j += 512) {
        unsigned long long rec = pk[j];
        unsigned lo = (unsigned)rec;
        float vv = __int_as_float((int)(unsigned)(rec >> 32));
        int r = (int)(lo & (BROWS - 1));
        int q = atomicAdd(&cur[r], 1);
        epk[s + q] = ((lo >> BSHIFT) << 14) | (unsigned)f2q(vv * 16.f);
    }
}

// Zq = fp8(X @ W1), X:[n,5]. Wave per row, lane = out dim.
__global__ __launch_bounds__(256) void dense5_k(
    const float* __restrict__ X, const float* __restrict__ W,
    unsigned char* __restrict__ Zq, int n) {
    int lane = threadIdx.x & 63;
    int row = (blockIdx.x * blockDim.x + threadIdx.x) >> 6;
    if (row >= n) return;
    float w0 = W[lane], w1 = W[64 + lane], w2 = W[128 + lane],
          w3 = W[192 + lane], w4 = W[256 + lane];
    float xv = (lane < 5) ? X[(size_t)row * 5 + lane] : 0.f;
    float y = __shfl(xv, 0, 64) * w0;
    y = fmaf(__shfl(xv, 1, 64), w1, y);
    y = fmaf(__shfl(xv, 2, 64), w2, y);
    y = fmaf(__shfl(xv, 3, 64), w3, y);
    y = fmaf(__shfl(xv, 4, 64), w4, y);
    Zq[(size_t)row * 64 + lane] = f2q(y);
}

// dense64 v7: Zq = fp8(X @ W) via mfma_f32_16x16x32_bf16. W staged into LDS
// coalesced once per block (v5/v6: 64 stride-256B scalar loads per wave =
// 16 lines per instruction). LDS stride 65: fragment read bank =
// (k*65 + 16c + l15) % 32 varies with k -> lk groups on distinct banks.
// Wave = 16-row tile x 64 cols; frag (c,m) holds B[k=32m+8lk+i][col=16c+l15].
__global__ __launch_bounds__(256, 4) void dense64_k(
    const float* __restrict__ X, const float* __restrict__ W,
    unsigned char* __restrict__ Zq, int n) {
    __shared__ float wlds[64 * 65];
    int tx = threadIdx.x;
    int lane = tx & 63, wid = tx >> 6;
    int l15 = lane & 15, lk = lane >> 4;
#pragma unroll
    for (int i = 0; i < 16; ++i) {
        int idx = i * 256 + tx;              // coalesced: 1KB per instr
        wlds[(idx >> 6) * 65 + (idx & 63)] = W[idx];
    }
    __syncthreads();
    bf16x8 bw[4][2];
#pragma unroll
    for (int c = 0; c < 4; ++c) {
#pragma unroll
        for (int m = 0; m < 2; ++m) {
            const float* wp = wlds + (32 * m + 8 * lk) * 65 + 16 * c + l15;
            f32x4 lo, hi;
            lo.x = wp[0];       lo.y = wp[65];      lo.z = wp[130];  lo.w = wp[195];
            hi.x = wp[260];     hi.y = wp[325];     hi.z = wp[390];  hi.w = wp[455];
            bw[c][m] = pack_bf8(lo, hi);
        }
    }
    int nt = (n + 15) >> 4;
    int nwv = (int)(gridDim.x * 4);
    for (int t = blockIdx.x * 4 + wid; t < nt; t += nwv) {
        int rowb = t << 4;
        int ar = min(rowb + l15, n - 1);  // clamped A row (stores guarded)
        const float* xr = X + (size_t)ar * 64 + 8 * lk;
        f32x4 a0 = *(const f32x4*)(xr);
        f32x4 a1 = *(const f32x4*)(xr + 4);
        f32x4 a2 = *(const f32x4*)(xr + 32);
        f32x4 a3 = *(const f32x4*)(xr + 36);
        bf16x8 A0 = pack_bf8(a0, a1);
        bf16x8 A1 = pack_bf8(a2, a3);
        f32x4 acc0 = 0, acc1 = 0, acc2 = 0, acc3 = 0;
        acc0 = __builtin_amdgcn_mfma_f32_16x16x32_bf16(A0, bw[0][0], acc0, 0, 0, 0);
        acc1 = __builtin_amdgcn_mfma_f32_16x16x32_bf16(A0, bw[1][0], acc1, 0, 0, 0);
        acc2 = __builtin_amdgcn_mfma_f32_16x16x32_bf16(A0, bw[2][0], acc2, 0, 0, 0);
        acc3 = __builtin_amdgcn_mfma_f32_16x16x32_bf16(A0, bw[3][0], acc3, 0, 0, 0);
        acc0 = __builtin_amdgcn_mfma_f32_16x16x32_bf16(A1, bw[0][1], acc0, 0, 0, 0);
        acc1 = __builtin_amdgcn_mfma_f32_16x16x32_bf16(A1, bw[1][1], acc1, 0, 0, 0);
        acc2 = __builtin_amdgcn_mfma_f32_16x16x32_bf16(A1, bw[2][1], acc2, 0, 0, 0);
        acc3 = __builtin_amdgcn_mfma_f32_16x16x32_bf16(A1, bw[3][1], acc3, 0, 0, 0);
#pragma unroll
        for (int j = 0; j < 4; ++j) {
            int r = rowb + 4 * lk + j;
            if (r < n) {
                unsigned char* zp = Zq + (size_t)r * 64 + l15;
                zp[0]  = f2q(acc0[j]);
                zp[16] = f2q(acc1[j]);
                zp[32] = f2q(acc2[j]);
                zp[48] = f2q(acc3[j]);
            }
        }
    }
}

// Packed core: one edge's 16B Zq chunk into a2[0..7] (f32x2 = 2 dims each).
// 8 cvt_pk + 8 pk_fma per edge.
#define FMA16P(vv2, d)                                                         \
    a2[0] += (vv2) * q2f2<0>((d).x);                                           \
    a2[1] += (vv2) * q2f2<1>((d).x);                                           \
    a2[2] += (vv2) * q2f2<0>((d).y);                                           \
    a2[3] += (vv2) * q2f2<1>((d).y);                                           \
    a2[4] += (vv2) * q2f2<0>((d).z);                                           \
    a2[5] += (vv2) * q2f2<1>((d).z);                                           \
    a2[6] += (vv2) * q2f2<0>((d).w);                                           \
    a2[7] += (vv2) * q2f2<1>((d).w);

// spmm v7: wave per row; 16 edge-slots (lane>>2) x 4 dim-lanes (lane&3).
// One dwordx4 gather = 16 lines in flight. Predicated tail body (clamped
// index, v masked 0; Zq is NaN-free since cvt_pk_fp8_f32 saturates).
// row forced scalar -> rp pair via s_load; epilogue setup after gathers.
template <int L3>
__global__ __launch_bounds__(256, 8) void spmm16_k(
    const int* __restrict__ rp, const unsigned* __restrict__ epk,
    const unsigned char* __restrict__ Zq, const float* __restrict__ bias,
    const float* __restrict__ xa, const float* __restrict__ xb,
    float* __restrict__ xout, int n) {
    int lane = threadIdx.x & 63;
    int dim4 = lane & 3, slot = lane >> 2;
    int row = __builtin_amdgcn_readfirstlane(
        (int)((blockIdx.x * blockDim.x + threadIdx.x) >> 6));
    if (row >= n) return;
    int s = rp[row], e = rp[row + 1];    // scalar loads (wave-uniform row)
    const unsigned char* zb = Zq + (dim4 << 4);

    f32x2 a2[8];
#pragma unroll
    for (int k = 0; k < 8; ++k) a2[k] = 0;

    int j = s;
    for (; j + 32 <= e; j += 32) {  // 2 c-loads + 2 gathers, loads first
        unsigned c0 = __builtin_nontemporal_load(epk + j + slot);
        unsigned c1 = __builtin_nontemporal_load(epk + j + 16 + slot);
        u32x4 d0 = *(const u32x4*)(zb + (c0 >> 8));  // c>>8 = col*64
        u32x4 d1 = *(const u32x4*)(zb + (c1 >> 8));
        float v0 = q2f<0>(c0);
        float v1 = q2f<0>(c1);
        f32x2 vv0 = {v0, v0}, vv1 = {v1, v1};
        FMA16P(vv0, d0)
        FMA16P(vv1, d1)
    }
    if (j < e) {  // predicated 32-edge body: whole remainder in one burst
        int i0 = min(j + slot, e - 1);
        int i1 = min(j + 16 + slot, e - 1);
        unsigned c0 = __builtin_nontemporal_load(epk + i0);
        unsigned c1 = __builtin_nontemporal_load(epk + i1);
        u32x4 d0 = *(const u32x4*)(zb + (c0 >> 8));
        u32x4 d1 = *(const u32x4*)(zb + (c1 >> 8));
        float v0 = (j + slot < e) ? q2f<0>(c0) : 0.f;
        float v1 = (j + 16 + slot < e) ? q2f<0>(c1) : 0.f;
        f32x2 vv0 = {v0, v0}, vv1 = {v1, v1};
        FMA16P(vv0, d0)
        FMA16P(vv1, d1)
    }

    // epilogue-only setup: issued after the gather chain is in flight
    int dimL = dim4 * 16 + ((lane >> 2) & 1) * 8 + ((lane >> 3) & 1) * 4 +
               ((lane >> 4) & 1) * 2 + ((lane >> 5) & 1);
    float bv = bias[dimL];
    float ra = 0.f, rb = 0.f;
    if (L3) {
        ra = __builtin_nontemporal_load(xa + (size_t)row * 64 + dimL);
        rb = __builtin_nontemporal_load(xb + (size_t)row * 64 + dimL);
    }

    // re-extract scalars (constant indices -> stays in registers)
    float a[16];
#pragma unroll
    for (int k = 0; k < 16; ++k) a[k] = a2[k >> 1][k & 1];

    // recursive-halving reduce over 16 slots with dim-splitting:
    // each round keep half the dims, donate the other half to the partner.
    float r8[8];
    {
        bool h = (lane & 4) != 0;
#pragma unroll
        for (int k = 0; k < 8; ++k) {
            float keep = h ? a[8 + k] : a[k];
            float give = h ? a[k] : a[8 + k];
            r8[k] = keep + __shfl_xor(give, 4, 64);
        }
    }
    float r4[4];
    {
        bool h = (lane & 8) != 0;
#pragma unroll
        for (int k = 0; k < 4; ++k) {
            float keep = h ? r8[4 + k] : r8[k];
            float give = h ? r8[k] : r8[4 + k];
            r4[k] = keep + __shfl_xor(give, 8, 64);
        }
    }
    float r2[2];
    {
        bool h = (lane & 16) != 0;
#pragma unroll
        for (int k = 0; k < 2; ++k) {
            float keep = h ? r4[2 + k] : r4[k];
            float give = h ? r4[k] : r4[2 + k];
            r2[k] = keep + __shfl_xor(give, 16, 64);
        }
    }
    float tot;
    {
        bool h = (lane & 32) != 0;
        float keep = h ? r2[1] : r2[0];
        float give = h ? r2[0] : r2[1];
        tot = keep + __shfl_xor(give, 32, 64);
    }

    float o = fmaxf(fmaf(tot, 0.0625f, bv), 0.f);
    if (L3) o += ra + rb;
    xout[(size_t)row * 64 + dimL] = o;  // all 64 lanes store (256B/row)
}

// Pool: batch sorted -> run-length accumulate NODE_CHUNK nodes per wave, one
// atomicAdd per segment boundary per lane. h already = x1+x2+x3.
#define NODE_CHUNK 16
__global__ void pool_k(const float* __restrict__ h, const int* __restrict__ batch,
                       float* __restrict__ sums, int* __restrict__ cnts, int n) {
    int lane = threadIdx.x & 63;
    int w = (blockIdx.x * blockDim.x + threadIdx.x) >> 6;
    int node0 = w * NODE_CHUNK;
    if (node0 >= n) return;
    int cur = batch[node0];
    float acc = 0.f;
    int cnt = 0;
    int end = min(node0 + NODE_CHUNK, n);
    for (int nd = node0; nd < end; ++nd) {
        int bg = batch[nd];  // wave-uniform
        if (bg != cur) {
            atomicAdd(&sums[(size_t)cur * 64 + lane], acc);
            if (lane == 0) atomicAdd(&cnts[cur], cnt);
            acc = 0.f;
            cnt = 0;
            cur = bg;
        }
        acc += h[(size_t)nd * 64 + lane];
        cnt++;
    }
    atomicAdd(&sums[(size_t)cur * 64 + lane], acc);
    if (lane == 0) atomicAdd(&cnts[cur], cnt);
}

// Head: pooled = sums/(3*cnt); out = softmax(pooled @ Wl + bl). Wave per graph.
__global__ void final_k(const float* __restrict__ sums, const int* __restrict__ cnts,
                        const float* __restrict__ Wl, const float* __restrict__ bl,
                        float* __restrict__ out, int G) {
    int lane = threadIdx.x & 63;
    int g = (blockIdx.x * blockDim.x + threadIdx.x) >> 6;
    if (g >= G) return;
    float c = (float)max(cnts[g], 1);
    float s = sums[(size_t)g * 64 + lane] / (3.f * c);
    float y = (lane < 10) ? bl[lane] : -1e30f;
    for (int k = 0; k < 64; ++k) {
        float sk = __shfl(s, k, 64);
        if (lane < 10) y = fmaf(sk, Wl[k * 10 + lane], y);
    }
    float m = y;
#pragma unroll
    for (int off = 8; off; off >>= 1) m = fmaxf(m, __shfl_xor(m, off, 16));
    float ey = (lane < 10) ? __expf(y - m) : 0.f;
    float sm = ey;
#pragma unroll
    for (int off = 8; off; off >>= 1) sm += __shfl_xor(sm, off, 16);
    if (lane < 10) out[(size_t)g * 10 + lane] = ey / sm;
}

extern "C" void kernel_launch(void* const* d_in, const int* in_sizes, int n_in,
                              void* d_out, int out_size, void* d_ws, size_t ws_size,
                              hipStream_t stream) {
    const float* x = (const float*)d_in[0];
    const int* rows = (const int*)d_in[1];
    const int* cols = (const int*)d_in[2];
    const float* vals = (const float*)d_in[3];
    const int* batch = (const int*)d_in[4];
    const float* W1 = (const float*)d_in[5];
    const float* b1 = (const float*)d_in[6];
    const float* W2 = (const float*)d_in[7];
    const float* b2 = (const float*)d_in[8];
    const float* W3 = (const float*)d_in[9];
    const float* b3 = (const float*)d_in[10];
    const float* Wl = (const float*)d_in[11];
    const float* bl = (const float*)d_in[12];
    float* out = (float*)d_out;

    const int N = in_sizes[4];   // n_nodes (<= 131072)
    const int E = in_sizes[1];   // n_edges
    const int G = out_size / 10; // n_graphs
    const int K = (N + BROWS - 1) >> BSHIFT;

    char* p = (char*)d_ws;
    size_t off = 0;
    auto alloc = [&](size_t bytes) -> void* {
        off = (off + 255) & ~(size_t)255;
        void* r = (void*)(p + off);
        off += bytes;
        return r;
    };
    size_t featF = (size_t)N * 64 * 4;
    int* bhist = (int*)alloc(MAXK * 4);
    int* bstart = (int*)alloc((MAXK + 1) * 4);
    int* bcur = (int*)alloc(MAXK * 16 * 4);
    int* rp = (int*)alloc((size_t)(N + 2) * 4);
    // pk (bucketed, pre-sort) is dead after sort_k; alias with h (written
    // only by the layer-3 spmm, far after sort_k).
    void* regP = alloc((size_t)E * 8 > featF ? (size_t)E * 8 : featF);
    unsigned* epk = (unsigned*)alloc((size_t)E * 4);  // packed sorted edges
    unsigned char* ZqA = (unsigned char*)alloc((size_t)N * 64);
    unsigned char* ZqB = (unsigned char*)alloc((size_t)N * 64);
    float* x1 = (float*)alloc(featF);
    float* x2 = (float*)alloc(featF);
    float* sums = (float*)alloc((size_t)G * 64 * 4);
    int* cnts = (int*)alloc((size_t)G * 4);

    unsigned long long* pk = (unsigned long long*)regP;
    float* h = (float*)regP;

    (void)hipMemsetAsync(bhist, 0, MAXK * 4, stream);

    int cb = (E + CHUNK - 1) / CHUNK;
    bhist_k<<<cb, 512, 0, stream>>>(rows, bhist, E);
    bscan_k<<<1, MAXK, 0, stream>>>(bhist, bstart, bcur, rp, sums, cnts, K, E, N, G);
    binpass_k<<<cb, 512, 0, stream>>>(rows, cols, vals, bcur, pk, E);
    sort_k<<<K, 512, 0, stream>>>(bstart, pk, rp, epk, N);

    int rb = (N + 3) / 4;  // wave-per-row blocks
    dense5_k<<<rb, 256, 0, stream>>>(x, W1, ZqA, N);
    spmm16_k<0><<<rb, 256, 0, stream>>>(rp, epk, ZqA, b1, nullptr, nullptr, x1, N);
    dense64_k<<<512, 256, 0, stream>>>(x1, W2, ZqB, N);
    spmm16_k<0><<<rb, 256, 0, stream>>>(rp, epk, ZqB, b2, nullptr, nullptr, x2, N);
    dense64_k<<<512, 256, 0, stream>>>(x2, W3, ZqA, N);
    spmm16_k<1><<<rb, 256, 0, stream>>>(rp, epk, ZqA, b3, x1, x2, h, N);

    int pw = (N + NODE_CHUNK - 1) / NODE_CHUNK;
    pool_k<<<(pw + 3) / 4, 256, 0, stream>>>(h, batch, sums, cnts, N);
    final_k<<<(G + 3) / 4, 256, 0, stream>>>(sums, cnts, Wl, bl, out, G);
}

// Round 8
// 361.815 us; speedup vs baseline: 1.7985x; 1.0290x over previous
//
#include <hip/hip_runtime.h>

// GCN3: 3x (COO spmm -> Linear(64) -> ReLU), segment-mean pool, softmax head.
// relu(spmm(X)@W + b) == relu(spmm(X@W) + b): dense transform first, then
// PULL-spmm from fp8 Z (e4m3, 64B/row). Edge record 4B: (col<<14)|fp8(val*16)
// (col pre-scaled so gather byte-offset is just rec>>8).
// spmm v8: ONE predicated 64-slot burst per row (4 c-loads -> 4 gathers, 64
// lines in flight; idx clamped to e-1, v masked 0). P(deg<=64)=1-6e-7 ->
// virtually every row = exactly one serial memory round (v7: deg>32 rows =
// 2 serial bursts; avg 1.55 rounds). Slots processed 61->64 avg (+5% VALU).
// Rare deg>64: unpredicated 64-bursts first. Packed cvt_pk_f32_fp8 + f32x2
// acc; scalar row (readfirstlane) -> rp via s_load; epilogue setup deferred.
// dense64: MFMA 16x16x32 bf16, W staged in LDS per block.
// CSR build: LDS-staged binpass into 512-row buckets, per-bucket counting
// sort. Pool fusion into spmm3 REJECTED: 6.4M lane-atomics ~25us > pool 3.5.

#define BSHIFT 9
#define BROWS  (1 << BSHIFT)   // 512 rows per bucket
#define MAXK   256             // supports N <= 131072
#define CHUNK  6144            // edges per binpass/bhist block

typedef float f32x2 __attribute__((ext_vector_type(2)));
typedef float f32x4 __attribute__((ext_vector_type(4)));
typedef unsigned u32x4 __attribute__((ext_vector_type(4)));
typedef short bf16x8 __attribute__((ext_vector_type(8)));

__device__ inline unsigned char f2q(float f) {  // fp8 e4m3 RNE (saturating)
    unsigned p = __builtin_amdgcn_cvt_pk_fp8_f32(f, f, 0u, false);
    return (unsigned char)(p & 0xffu);
}
template <int SEL>
__device__ inline float q2f(unsigned q) {  // byte-select fp8->f32 (SEL = ICE)
    return __builtin_amdgcn_cvt_f32_fp8(q, SEL);
}
template <int HI>  // 2 fp8 (bytes 2*HI, 2*HI+1) -> 2 f32, one instr
__device__ inline f32x2 q2f2(unsigned q) {
#if __has_builtin(__builtin_amdgcn_cvt_pk_f32_fp8)
    return __builtin_amdgcn_cvt_pk_f32_fp8(q, HI != 0);
#else
    f32x2 r;
    r.x = q2f<2 * HI>(q);
    r.y = q2f<2 * HI + 1>(q);
    return r;
#endif
}

// pack 8 f32 (k ascending: lo.x..lo.w, hi.x..hi.w) -> bf16x8, RNE
__device__ inline bf16x8 pack_bf8(f32x4 lo, f32x4 hi) {
    union { u32x4 u; bf16x8 h; } r;
    asm("v_cvt_pk_bf16_f32 %0, %1, %2" : "=v"(r.u.x) : "v"(lo.x), "v"(lo.y));
    asm("v_cvt_pk_bf16_f32 %0, %1, %2" : "=v"(r.u.y) : "v"(lo.z), "v"(lo.w));
    asm("v_cvt_pk_bf16_f32 %0, %1, %2" : "=v"(r.u.z) : "v"(hi.x), "v"(hi.y));
    asm("v_cvt_pk_bf16_f32 %0, %1, %2" : "=v"(r.u.w) : "v"(hi.z), "v"(hi.w));
    return r.h;
}

// Per-block LDS histogram of bucket ids -> global bucket counts.
// Also zeroes the pool buffers (sums/cnts), grid-strided (was in single-block
// bscan_k -> serial 64KB store burden on one CU).
__global__ __launch_bounds__(512) void bhist_k(const int* __restrict__ rows,
                                               int* __restrict__ bhist,
                                               float* __restrict__ sums,
                                               int* __restrict__ cnts,
                                               int E, int G) {
    __shared__ int h[MAXK];
    int tx = threadIdx.x;
    if (tx < MAXK) h[tx] = 0;
    int gstep = gridDim.x * 512, gid = blockIdx.x * 512 + tx;
    f32x4* s4 = (f32x4*)sums;
    for (int i = gid; i < G * 16; i += gstep) s4[i] = 0;
    for (int i = gid; i < G; i += gstep) cnts[i] = 0;
    __syncthreads();
    int e0 = blockIdx.x * CHUNK, ee = min(e0 + CHUNK, E);
    for (int e = e0 + tx; e < ee; e += 512)
        atomicAdd(&h[rows[e] >> BSHIFT], 1);
    __syncthreads();
    if (tx < MAXK && h[tx]) atomicAdd(&bhist[tx], h[tx]);
}

// Exclusive scan of bucket counts (single block); init padded cursors; rp[N]=E.
__global__ __launch_bounds__(MAXK) void bscan_k(const int* __restrict__ bhist,
                                                int* __restrict__ bstart,
                                                int* __restrict__ bcur,
                                                int* __restrict__ rp,
                                                int K, int E, int N) {
    __shared__ int s[MAXK];
    int tx = threadIdx.x;
    int v = (tx < K) ? bhist[tx] : 0;
    s[tx] = v;
    __syncthreads();
    for (int off = 1; off < MAXK; off <<= 1) {
        int t = (tx >= off) ? s[tx - off] : 0;
        __syncthreads();
        s[tx] += t;
        __syncthreads();
    }
    if (tx < K) {
        bstart[tx] = s[tx] - v;
        bcur[tx * 16] = s[tx] - v;  // 1 cursor per 64B line
    }
    if (tx == K - 1) bstart[K] = E;
    if (tx == 0) rp[N] = E;
}

// Bin edges by 512-row bucket, staged in LDS so global writes are ~31-edge
// single-CU bursts. Record (u64): lo32=(col<<9)|(row&511), hi32=val bits.
__global__ __launch_bounds__(512) void binpass_k(
    const int* __restrict__ rows, const int* __restrict__ cols,
    const float* __restrict__ vals, int* __restrict__ bcur,
    unsigned long long* __restrict__ pk, int E) {
    __shared__ int h[MAXK], base[MAXK], gbase[MAXK], lcnt[MAXK];
    __shared__ unsigned long long st[CHUNK];  // 48 KB
    int tx = threadIdx.x;
    if (tx < MAXK) h[tx] = 0;
    __syncthreads();
    int e0 = blockIdx.x * CHUNK, ee = min(e0 + CHUNK, E);
    for (int e = e0 + tx; e < ee; e += 512)
        atomicAdd(&h[rows[e] >> BSHIFT], 1);
    __syncthreads();
    int v = (tx < MAXK) ? h[tx] : 0;
    if (tx < MAXK) lcnt[tx] = v;  // scan buffer
    __syncthreads();
    for (int off = 1; off < MAXK; off <<= 1) {
        int t = (tx >= off && tx < MAXK) ? lcnt[tx - off] : 0;
        __syncthreads();
        if (tx < MAXK) lcnt[tx] += t;
        __syncthreads();
    }
    if (tx < MAXK) {
        base[tx] = lcnt[tx] - v;
        if (v) gbase[tx] = atomicAdd(&bcur[tx * 16], v);
        lcnt[tx] = 0;
    }
    __syncthreads();
    for (int e = e0 + tx; e < ee; e += 512) {
        int r = rows[e];
        int c = cols[e];
        float vv = vals[e];
        int b = r >> BSHIFT;
        int p = base[b] + atomicAdd(&lcnt[b], 1);
        unsigned lo = ((unsigned)c << BSHIFT) | (unsigned)(r & (BROWS - 1));
        st[p] = (unsigned long long)lo
              | ((unsigned long long)(unsigned)__float_as_int(vv) << 32);
    }
    __syncthreads();
    // flush contiguous per-bucket runs, wave-parallel. NT safe: 64 lanes x 8B
    // = 512B contiguous per instruction (full lines covered).
    int lane = tx & 63, wid = tx >> 6;
    for (int b = wid; b < MAXK; b += 8) {
        int cnt = h[b];
        if (!cnt) continue;
        int lb = base[b], gb = gbase[b];
        for (int i = lane; i < cnt; i += 64)
            __builtin_nontemporal_store(st[lb + i], &pk[gb + i]);
    }
}

// Per-bucket counting sort: one block per bucket. LDS hist over 512 rows,
// scan -> rp, then local scatter into the bucket's contiguous epk window.
// CACHED loads/stores (sub-line scatter: L2 must assemble the lines).
// Output record (4B): (col << 14) | fp8(val * 16)  [col<<14 = byteoff<<8].
__global__ __launch_bounds__(512) void sort_k(
    const int* __restrict__ bstart, const unsigned long long* __restrict__ pk,
    int* __restrict__ rp, unsigned* __restrict__ epk, int n) {
    __shared__ int hist[BROWS], cur[BROWS];
    int tx = threadIdx.x;
    int b = blockIdx.x;
    int row0 = b << BSHIFT;
    int s = bstart[b], e = bstart[b + 1];
    hist[tx] = 0;
    __syncthreads();
    for (int j = s + tx; j < e; j += 512) {
        unsigned lo = (unsigned)pk[j];
        atomicAdd(&hist[lo & (BROWS - 1)], 1);
    }
    __syncthreads();
    int v = hist[tx];
    for (int off = 1; off < BROWS; off <<= 1) {
        int t = (tx >= off) ? hist[tx - off] : 0;
        __syncthreads();
        hist[tx] += t;
        __syncthreads();
    }
    int excl = hist[tx] - v;
    cur[tx] = excl;
    if (row0 + tx < n) rp[row0 + tx] = s + excl;
    __syncthreads();
    for (int j = s + tx; j < e; j += 512) {
        unsigned long long rec = pk[j];
        unsigned lo = (unsigned)rec;
        float vv = __int_as_float((int)(unsigned)(rec >> 32));
        int r = (int)(lo & (BROWS - 1));
        int q = atomicAdd(&cur[r], 1);
        epk[s + q] = ((lo >> BSHIFT) << 14) | (unsigned)f2q(vv * 16.f);
    }
}

// Zq = fp8(X @ W1), X:[n,5]. Wave per row, lane = out dim.
__global__ __launch_bounds__(256) void dense5_k(
    const float* __restrict__ X, const float* __restrict__ W,
    unsigned char* __restrict__ Zq, int n) {
    int lane = threadIdx.x & 63;
    int row = (blockIdx.x * blockDim.x + threadIdx.x) >> 6;
    if (row >= n) return;
    float w0 = W[lane], w1 = W[64 + lane], w2 = W[128 + lane],
          w3 = W[192 + lane], w4 = W[256 + lane];
    float xv = (lane < 5) ? X[(size_t)row * 5 + lane] : 0.f;
    float y = __shfl(xv, 0, 64) * w0;
    y = fmaf(__shfl(xv, 1, 64), w1, y);
    y = fmaf(__shfl(xv, 2, 64), w2, y);
    y = fmaf(__shfl(xv, 3, 64), w3, y);
    y = fmaf(__shfl(xv, 4, 64), w4, y);
    Zq[(size_t)row * 64 + lane] = f2q(y);
}

// dense64: Zq = fp8(X @ W) via mfma_f32_16x16x32_bf16. W staged into LDS
// coalesced once per block. LDS stride 65 -> conflict-free fragment reads.
// Wave = 16-row tile x 64 cols; frag (c,m) holds B[k=32m+8lk+i][col=16c+l15].
__global__ __launch_bounds__(256, 4) void dense64_k(
    const float* __restrict__ X, const float* __restrict__ W,
    unsigned char* __restrict__ Zq, int n) {
    __shared__ float wlds[64 * 65];
    int tx = threadIdx.x;
    int lane = tx & 63, wid = tx >> 6;
    int l15 = lane & 15, lk = lane >> 4;
#pragma unroll
    for (int i = 0; i < 16; ++i) {
        int idx = i * 256 + tx;              // coalesced: 1KB per instr
        wlds[(idx >> 6) * 65 + (idx & 63)] = W[idx];
    }
    __syncthreads();
    bf16x8 bw[4][2];
#pragma unroll
    for (int c = 0; c < 4; ++c) {
#pragma unroll
        for (int m = 0; m < 2; ++m) {
            const float* wp = wlds + (32 * m + 8 * lk) * 65 + 16 * c + l15;
            f32x4 lo, hi;
            lo.x = wp[0];       lo.y = wp[65];      lo.z = wp[130];  lo.w = wp[195];
            hi.x = wp[260];     hi.y = wp[325];     hi.z = wp[390];  hi.w = wp[455];
            bw[c][m] = pack_bf8(lo, hi);
        }
    }
    int nt = (n + 15) >> 4;
    int nwv = (int)(gridDim.x * 4);
    for (int t = blockIdx.x * 4 + wid; t < nt; t += nwv) {
        int rowb = t << 4;
        int ar = min(rowb + l15, n - 1);  // clamped A row (stores guarded)
        const float* xr = X + (size_t)ar * 64 + 8 * lk;
        f32x4 a0 = *(const f32x4*)(xr);
        f32x4 a1 = *(const f32x4*)(xr + 4);
        f32x4 a2 = *(const f32x4*)(xr + 32);
        f32x4 a3 = *(const f32x4*)(xr + 36);
        bf16x8 A0 = pack_bf8(a0, a1);
        bf16x8 A1 = pack_bf8(a2, a3);
        f32x4 acc0 = 0, acc1 = 0, acc2 = 0, acc3 = 0;
        acc0 = __builtin_amdgcn_mfma_f32_16x16x32_bf16(A0, bw[0][0], acc0, 0, 0, 0);
        acc1 = __builtin_amdgcn_mfma_f32_16x16x32_bf16(A0, bw[1][0], acc1, 0, 0, 0);
        acc2 = __builtin_amdgcn_mfma_f32_16x16x32_bf16(A0, bw[2][0], acc2, 0, 0, 0);
        acc3 = __builtin_amdgcn_mfma_f32_16x16x32_bf16(A0, bw[3][0], acc3, 0, 0, 0);
        acc0 = __builtin_amdgcn_mfma_f32_16x16x32_bf16(A1, bw[0][1], acc0, 0, 0, 0);
        acc1 = __builtin_amdgcn_mfma_f32_16x16x32_bf16(A1, bw[1][1], acc1, 0, 0, 0);
        acc2 = __builtin_amdgcn_mfma_f32_16x16x32_bf16(A1, bw[2][1], acc2, 0, 0, 0);
        acc3 = __builtin_amdgcn_mfma_f32_16x16x32_bf16(A1, bw[3][1], acc3, 0, 0, 0);
#pragma unroll
        for (int j = 0; j < 4; ++j) {
            int r = rowb + 4 * lk + j;
            if (r < n) {
                unsigned char* zp = Zq + (size_t)r * 64 + l15;
                zp[0]  = f2q(acc0[j]);
                zp[16] = f2q(acc1[j]);
                zp[32] = f2q(acc2[j]);
                zp[48] = f2q(acc3[j]);
            }
        }
    }
}

// Packed core: one edge's 16B Zq chunk into a2[0..7] (f32x2 = 2 dims each).
// 8 cvt_pk + 8 pk_fma per edge.
#define FMA16P(vv2, d)                                                         \
    a2[0] += (vv2) * q2f2<0>((d).x);                                           \
    a2[1] += (vv2) * q2f2<1>((d).x);                                           \
    a2[2] += (vv2) * q2f2<0>((d).y);                                           \
    a2[3] += (vv2) * q2f2<1>((d).y);                                           \
    a2[4] += (vv2) * q2f2<0>((d).z);                                           \
    a2[5] += (vv2) * q2f2<1>((d).z);                                           \
    a2[6] += (vv2) * q2f2<0>((d).w);                                           \
    a2[7] += (vv2) * q2f2<1>((d).w);

// spmm v8: wave per row; 16 edge-slots (lane>>2) x 4 dim-lanes (lane&3).
// ONE predicated 64-slot burst covers the whole row for deg<=64 (all but
// ~0 rows): 4 c-loads then 4 gathers = 64 lines in flight, ONE serial
// memory round per row. deg>64: unpredicated 64-bursts first.
template <int L3>
__global__ __launch_bounds__(256, 8) void spmm16_k(
    const int* __restrict__ rp, const unsigned* __restrict__ epk,
    const unsigned char* __restrict__ Zq, const float* __restrict__ bias,
    const float* __restrict__ xa, const float* __restrict__ xb,
    float* __restrict__ xout, int n) {
    int lane = threadIdx.x & 63;
    int dim4 = lane & 3, slot = lane >> 2;
    int row = __builtin_amdgcn_readfirstlane(
        (int)((blockIdx.x * blockDim.x + threadIdx.x) >> 6));
    if (row >= n) return;
    int s = rp[row], e = rp[row + 1];    // scalar loads (wave-uniform row)
    const unsigned char* zb = Zq + (dim4 << 4);

    f32x2 a2[8];
#pragma unroll
    for (int k = 0; k < 8; ++k) a2[k] = 0;

    int j = s;
    for (; j + 64 <= e; j += 64) {  // rare (P ~ 6e-7): full 64-bursts
        unsigned c0 = __builtin_nontemporal_load(epk + j + slot);
        unsigned c1 = __builtin_nontemporal_load(epk + j + 16 + slot);
        unsigned c2 = __builtin_nontemporal_load(epk + j + 32 + slot);
        unsigned c3 = __builtin_nontemporal_load(epk + j + 48 + slot);
        u32x4 d0 = *(const u32x4*)(zb + (c0 >> 8));  // c>>8 = col*64
        u32x4 d1 = *(const u32x4*)(zb + (c1 >> 8));
        u32x4 d2 = *(const u32x4*)(zb + (c2 >> 8));
        u32x4 d3 = *(const u32x4*)(zb + (c3 >> 8));
        float v0 = q2f<0>(c0), v1 = q2f<0>(c1);
        float v2 = q2f<0>(c2), v3 = q2f<0>(c3);
        f32x2 vv0 = {v0, v0}, vv1 = {v1, v1}, vv2 = {v2, v2}, vv3 = {v3, v3};
        FMA16P(vv0, d0)
        FMA16P(vv1, d1)
        FMA16P(vv2, d2)
        FMA16P(vv3, d3)
    }
    if (j < e) {  // the common case: whole row in ONE predicated burst
        int i0 = min(j + slot, e - 1);
        int i1 = min(j + 16 + slot, e - 1);
        int i2 = min(j + 32 + slot, e - 1);
        int i3 = min(j + 48 + slot, e - 1);
        unsigned c0 = __builtin_nontemporal_load(epk + i0);
        unsigned c1 = __builtin_nontemporal_load(epk + i1);
        unsigned c2 = __builtin_nontemporal_load(epk + i2);
        unsigned c3 = __builtin_nontemporal_load(epk + i3);
        u32x4 d0 = *(const u32x4*)(zb + (c0 >> 8));
        u32x4 d1 = *(const u32x4*)(zb + (c1 >> 8));
        u32x4 d2 = *(const u32x4*)(zb + (c2 >> 8));
        u32x4 d3 = *(const u32x4*)(zb + (c3 >> 8));
        float v0 = (j + slot < e) ? q2f<0>(c0) : 0.f;
        float v1 = (j + 16 + slot < e) ? q2f<0>(c1) : 0.f;
        float v2 = (j + 32 + slot < e) ? q2f<0>(c2) : 0.f;
        float v3 = (j + 48 + slot < e) ? q2f<0>(c3) : 0.f;
        f32x2 vv0 = {v0, v0}, vv1 = {v1, v1}, vv2 = {v2, v2}, vv3 = {v3, v3};
        FMA16P(vv0, d0)
        FMA16P(vv1, d1)
        FMA16P(vv2, d2)
        FMA16P(vv3, d3)
    }

    // epilogue-only setup: issued after the gather chain is in flight
    int dimL = dim4 * 16 + ((lane >> 2) & 1) * 8 + ((lane >> 3) & 1) * 4 +
               ((lane >> 4) & 1) * 2 + ((lane >> 5) & 1);
    float bv = bias[dimL];
    float ra = 0.f, rb = 0.f;
    if (L3) {
        ra = __builtin_nontemporal_load(xa + (size_t)row * 64 + dimL);
        rb = __builtin_nontemporal_load(xb + (size_t)row * 64 + dimL);
    }

    // re-extract scalars (constant indices -> stays in registers)
    float a[16];
#pragma unroll
    for (int k = 0; k < 16; ++k) a[k] = a2[k >> 1][k & 1];

    // recursive-halving reduce over 16 slots with dim-splitting:
    // each round keep half the dims, donate the other half to the partner.
    float r8[8];
    {
        bool h = (lane & 4) != 0;
#pragma unroll
        for (int k = 0; k < 8; ++k) {
            float keep = h ? a[8 + k] : a[k];
            float give = h ? a[k] : a[8 + k];
            r8[k] = keep + __shfl_xor(give, 4, 64);
        }
    }
    float r4[4];
    {
        bool h = (lane & 8) != 0;
#pragma unroll
        for (int k = 0; k < 4; ++k) {
            float keep = h ? r8[4 + k] : r8[k];
            float give = h ? r8[k] : r8[4 + k];
            r4[k] = keep + __shfl_xor(give, 8, 64);
        }
    }
    float r2[2];
    {
        bool h = (lane & 16) != 0;
#pragma unroll
        for (int k = 0; k < 2; ++k) {
            float keep = h ? r4[2 + k] : r4[k];
            float give = h ? r4[k] : r4[2 + k];
            r2[k] = keep + __shfl_xor(give, 16, 64);
        }
    }
    float tot;
    {
        bool h = (lane & 32) != 0;
        float keep = h ? r2[1] : r2[0];
        float give = h ? r2[0] : r2[1];
        tot = keep + __shfl_xor(give, 32, 64);
    }

    float o = fmaxf(fmaf(tot, 0.0625f, bv), 0.f);
    if (L3) o += ra + rb;
    xout[(size_t)row * 64 + dimL] = o;  // all 64 lanes store (256B/row)
}

// Pool: batch sorted -> run-length accumulate NODE_CHUNK nodes per wave, one
// atomicAdd per segment boundary per lane. h already = x1+x2+x3.
#define NODE_CHUNK 16
__global__ void pool_k(const float* __restrict__ h, const int* __restrict__ batch,
                       float* __restrict__ sums, int* __restrict__ cnts, int n) {
    int lane = threadIdx.x & 63;
    int w = (blockIdx.x * blockDim.x + threadIdx.x) >> 6;
    int node0 = w * NODE_CHUNK;
    if (node0 >= n) return;
    int cur = batch[node0];
    float acc = 0.f;
    int cnt = 0;
    int end = min(node0 + NODE_CHUNK, n);
    for (int nd = node0; nd < end; ++nd) {
        int bg = batch[nd];  // wave-uniform
        if (bg != cur) {
            atomicAdd(&sums[(size_t)cur * 64 + lane], acc);
            if (lane == 0) atomicAdd(&cnts[cur], cnt);
            acc = 0.f;
            cnt = 0;
            cur = bg;
        }
        acc += h[(size_t)nd * 64 + lane];
        cnt++;
    }
    atomicAdd(&sums[(size_t)cur * 64 + lane], acc);
    if (lane == 0) atomicAdd(&cnts[cur], cnt);
}

// Head: pooled = sums/(3*cnt); out = softmax(pooled @ Wl + bl). Wave per graph.
__global__ void final_k(const float* __restrict__ sums, const int* __restrict__ cnts,
                        const float* __restrict__ Wl, const float* __restrict__ bl,
                        float* __restrict__ out, int G) {
    int lane = threadIdx.x & 63;
    int g = (blockIdx.x * blockDim.x + threadIdx.x) >> 6;
    if (g >= G) return;
    float c = (float)max(cnts[g], 1);
    float s = sums[(size_t)g * 64 + lane] / (3.f * c);
    float y = (lane < 10) ? bl[lane] : -1e30f;
    for (int k = 0; k < 64; ++k) {
        float sk = __shfl(s, k, 64);
        if (lane < 10) y = fmaf(sk, Wl[k * 10 + lane], y);
    }
    float m = y;
#pragma unroll
    for (int off = 8; off; off >>= 1) m = fmaxf(m, __shfl_xor(m, off, 16));
    float ey = (lane < 10) ? __expf(y - m) : 0.f;
    float sm = ey;
#pragma unroll
    for (int off = 8; off; off >>= 1) sm += __shfl_xor(sm, off, 16);
    if (lane < 10) out[(size_t)g * 10 + lane] = ey / sm;
}

extern "C" void kernel_launch(void* const* d_in, const int* in_sizes, int n_in,
                              void* d_out, int out_size, void* d_ws, size_t ws_size,
                              hipStream_t stream) {
    const float* x = (const float*)d_in[0];
    const int* rows = (const int*)d_in[1];
    const int* cols = (const int*)d_in[2];
    const float* vals = (const float*)d_in[3];
    const int* batch = (const int*)d_in[4];
    const float* W1 = (const float*)d_in[5];
    const float* b1 = (const float*)d_in[6];
    const float* W2 = (const float*)d_in[7];
    const float* b2 = (const float*)d_in[8];
    const float* W3 = (const float*)d_in[9];
    const float* b3 = (const float*)d_in[10];
    const float* Wl = (const float*)d_in[11];
    const float* bl = (const float*)d_in[12];
    float* out = (float*)d_out;

    const int N = in_sizes[4];   // n_nodes (<= 131072)
    const int E = in_sizes[1];   // n_edges
    const int G = out_size / 10; // n_graphs
    const int K = (N + BROWS - 1) >> BSHIFT;

    char* p = (char*)d_ws;
    size_t off = 0;
    auto alloc = [&](size_t bytes) -> void* {
        off = (off + 255) & ~(size_t)255;
        void* r = (void*)(p + off);
        off += bytes;
        return r;
    };
    size_t featF = (size_t)N * 64 * 4;
    int* bhist = (int*)alloc(MAXK * 4);
    int* bstart = (int*)alloc((MAXK + 1) * 4);
    int* bcur = (int*)alloc(MAXK * 16 * 4);
    int* rp = (int*)alloc((size_t)(N + 2) * 4);
    // pk (bucketed, pre-sort) is dead after sort_k; alias with h (written
    // only by the layer-3 spmm, far after sort_k).
    void* regP = alloc((size_t)E * 8 > featF ? (size_t)E * 8 : featF);
    unsigned* epk = (unsigned*)alloc((size_t)E * 4);  // packed sorted edges
    unsigned char* ZqA = (unsigned char*)alloc((size_t)N * 64);
    unsigned char* ZqB = (unsigned char*)alloc((size_t)N * 64);
    float* x1 = (float*)alloc(featF);
    float* x2 = (float*)alloc(featF);
    float* sums = (float*)alloc((size_t)G * 64 * 4);
    int* cnts = (int*)alloc((size_t)G * 4);

    unsigned long long* pk = (unsigned long long*)regP;
    float* h = (float*)regP;

    (void)hipMemsetAsync(bhist, 0, MAXK * 4, stream);

    int cb = (E + CHUNK - 1) / CHUNK;
    bhist_k<<<cb, 512, 0, stream>>>(rows, bhist, sums, cnts, E, G);
    bscan_k<<<1, MAXK, 0, stream>>>(bhist, bstart, bcur, rp, K, E, N);
    binpass_k<<<cb, 512, 0, stream>>>(rows, cols, vals, bcur, pk, E);
    sort_k<<<K, 512, 0, stream>>>(bstart, pk, rp, epk, N);

    int rb = (N + 3) / 4;  // wave-per-row blocks
    dense5_k<<<rb, 256, 0, stream>>>(x, W1, ZqA, N);
    spmm16_k<0><<<rb, 256, 0, stream>>>(rp, epk, ZqA, b1, nullptr, nullptr, x1, N);
    dense64_k<<<512, 256, 0, stream>>>(x1, W2, ZqB, N);
    spmm16_k<0><<<rb, 256, 0, stream>>>(rp, epk, ZqB, b2, nullptr, nullptr, x2, N);
    dense64_k<<<512, 256, 0, stream>>>(x2, W3, ZqA, N);
    spmm16_k<1><<<rb, 256, 0, stream>>>(rp, epk, ZqA, b3, x1, x2, h, N);

    int pw = (N + NODE_CHUNK - 1) / NODE_CHUNK;
    pool_k<<<(pw + 3) / 4, 256, 0, stream>>>(h, batch, sums, cnts, N);
    final_k<<<(G + 3) / 4, 256, 0, stream>>>(sums, cnts, Wl, bl, out, G);
}